// Round 3
// baseline (994.020 us; speedup 1.0000x reference)
//
#include <hip/hip_runtime.h>
#include <math.h>

#define LRELU_SLOPE 0.01f
#define BN_EPS 1e-5f
#define DEG_SCALE 67108864.0f          /* 2^26 */
#define DEG_INV_SCALE 1.4901161e-8f    /* 2^-26 */
#define DEG_MASK 0xFFFFFFFFFFULL       /* low 40 bits */

static inline int ceil_div(int a, int b) { return (a + b - 1) / b; }

// ---------------- init: packed deg/cnt = (cnt=0, deg=1.0 fixed-point); zero fill ----------
__global__ void k_init(unsigned long long* __restrict__ packed, int* __restrict__ fill, int N) {
  int i = blockIdx.x * blockDim.x + threadIdx.x;
  if (i < N) { packed[i] = (unsigned long long)(1u << 26); fill[i] = 0; }
}

// ---------------- degree + per-dst edge count: ONE native u64 atomic per edge ----------
__global__ void k_edge_count(const int* __restrict__ ei, const float* __restrict__ w,
                             unsigned long long* __restrict__ packed, int E) {
  int e = blockIdx.x * blockDim.x + threadIdx.x;
  if (e >= E) return;
  int d = ei[E + e];            // dst row of edge_index
  unsigned int q = (unsigned int)__float2uint_rn(w[e] * DEG_SCALE);
  atomicAdd(&packed[d], (1ULL << 40) | (unsigned long long)q);
}

// ---------------- 2-level exclusive scan over edge counts (from packed) ----------------
__global__ void k_scan1(const unsigned long long* __restrict__ packed, int* __restrict__ out,
                        int* __restrict__ bsum, int n) {
  __shared__ int lds[256];
  const int t = threadIdx.x;
  const int base = blockIdx.x * 1024 + t * 4;
  int v0 = 0, v1 = 0, v2 = 0, v3 = 0;
  if (base + 0 < n) v0 = (int)(packed[base + 0] >> 40);
  if (base + 1 < n) v1 = (int)(packed[base + 1] >> 40);
  if (base + 2 < n) v2 = (int)(packed[base + 2] >> 40);
  if (base + 3 < n) v3 = (int)(packed[base + 3] >> 40);
  int s = v0 + v1 + v2 + v3;
  lds[t] = s;
  __syncthreads();
#pragma unroll
  for (int off = 1; off < 256; off <<= 1) {
    int y = 0;
    if (t >= off) y = lds[t - off];
    __syncthreads();
    if (t >= off) lds[t] += y;
    __syncthreads();
  }
  int incl = lds[t];
  int excl = incl - s;
  if (base + 0 < n) out[base + 0] = excl;
  if (base + 1 < n) out[base + 1] = excl + v0;
  if (base + 2 < n) out[base + 2] = excl + v0 + v1;
  if (base + 3 < n) out[base + 3] = excl + v0 + v1 + v2;
  if (t == 255) bsum[blockIdx.x] = incl;
}

__global__ void k_scan2(int* __restrict__ bsum, int nb) {  // in-place exclusive, nb<=256
  __shared__ int lds[256];
  int t = threadIdx.x;
  int v = (t < nb) ? bsum[t] : 0;
  lds[t] = v;
  __syncthreads();
#pragma unroll
  for (int off = 1; off < 256; off <<= 1) {
    int y = 0;
    if (t >= off) y = lds[t - off];
    __syncthreads();
    if (t >= off) lds[t] += y;
    __syncthreads();
  }
  if (t < nb) bsum[t] = lds[t] - v;
}

__global__ void k_scan3(int* __restrict__ rowstart, const int* __restrict__ bscan,
                        const unsigned long long* __restrict__ packed,
                        float* __restrict__ dinv, int N, int E) {
  int i = blockIdx.x * blockDim.x + threadIdx.x;
  if (i < N) {
    rowstart[i] += bscan[i >> 10];
    float d = (float)(packed[i] & DEG_MASK) * DEG_INV_SCALE;  // includes self-loop 1.0
    dinv[i] = (d > 0.0f) ? rsqrtf(d) : 0.0f;
  }
  if (i == N) rowstart[N] = E;
}

// ---------------- CSR fill: col[p]=src, val[p]=w*dinv[src] ----------------
__global__ void k_fill(const int* __restrict__ ei, const float* __restrict__ w,
                       const int* __restrict__ rowstart, int* __restrict__ fill,
                       const float* __restrict__ dinv, int* __restrict__ col,
                       float* __restrict__ val, int E) {
  int e = blockIdx.x * blockDim.x + threadIdx.x;
  if (e >= E) return;
  int s = ei[e];
  int d = ei[E + e];
  int p = rowstart[d] + atomicAdd(&fill[d], 1);
  col[p] = s;
  val[p] = w[e] * dinv[s];
}

// ---------------- GEMM: H[N,64] = X[N,K] @ W[K,64]  (fp32, VALU) ----------------
template <int K>
__launch_bounds__(256)
__global__ void k_gemm(const float* __restrict__ X, const float* __restrict__ W,
                       float* __restrict__ H, int N) {
  __shared__ float xl[256 * 33];
  const int t = threadIdx.x;
  const int node = blockIdx.x * 256 + t;
  float acc[64];
#pragma unroll
  for (int j = 0; j < 64; ++j) acc[j] = 0.0f;

  for (int kt = 0; kt < K; kt += 32) {
    __syncthreads();  // protect previous tile reads
#pragma unroll
    for (int l = 0; l < 8; ++l) {
      int row = (t >> 3) + l * 32;
      int kc = (t & 7) * 4;
      int gn = blockIdx.x * 256 + row;
      float4 v = make_float4(0.f, 0.f, 0.f, 0.f);
      if (gn < N) v = *(const float4*)(X + (size_t)gn * K + kt + kc);
      float* p = &xl[row * 33 + kc];
      p[0] = v.x; p[1] = v.y; p[2] = v.z; p[3] = v.w;
    }
    __syncthreads();
#pragma unroll 4
    for (int k = 0; k < 32; ++k) {
      float xv = xl[t * 33 + k];
      const float4* Wr = (const float4*)(W + (size_t)(kt + k) * 64);
#pragma unroll
      for (int j4 = 0; j4 < 16; ++j4) {
        float4 wv = Wr[j4];
        acc[4 * j4 + 0] += xv * wv.x;
        acc[4 * j4 + 1] += xv * wv.y;
        acc[4 * j4 + 2] += xv * wv.z;
        acc[4 * j4 + 3] += xv * wv.w;
      }
    }
  }
  if (node < N) {
#pragma unroll
    for (int j4 = 0; j4 < 16; ++j4) {
      float4 o = make_float4(acc[4 * j4 + 0], acc[4 * j4 + 1], acc[4 * j4 + 2], acc[4 * j4 + 3]);
      *(float4*)(H + (size_t)node * 64 + 4 * j4) = o;
    }
  }
}

// ---------------- CSR aggregation: out[d] = dinv[d]*sum(val*h[src]) + dinv[d]^2*h[d] + b ----
__launch_bounds__(256)
__global__ void k_agg(const float* __restrict__ hin, float* __restrict__ hout,
                      const float* __restrict__ bias, const float* __restrict__ dinv,
                      const int* __restrict__ rowstart, const int* __restrict__ col,
                      const float* __restrict__ val, int N, int apply_lrelu) {
  const int t = threadIdx.x;
  const int grp = t >> 4;
  const int lane = t & 15;
  const int d = blockIdx.x * 16 + grp;
  if (d >= N) return;
  const int r0 = rowstart[d];
  const int r1 = rowstart[d + 1];
  float4 acc = make_float4(0.f, 0.f, 0.f, 0.f);
  for (int r = r0; r < r1; ++r) {
    int s = col[r];
    float v = val[r];
    float4 hv = *(const float4*)(hin + (size_t)s * 64 + lane * 4);
    acc.x += v * hv.x;
    acc.y += v * hv.y;
    acc.z += v * hv.z;
    acc.w += v * hv.w;
  }
  float di = dinv[d];
  float di2 = di * di;
  float4 hd = *(const float4*)(hin + (size_t)d * 64 + lane * 4);
  float4 b4 = *(const float4*)(bias + lane * 4);
  float4 o;
  o.x = di * acc.x + di2 * hd.x + b4.x;
  o.y = di * acc.y + di2 * hd.y + b4.y;
  o.z = di * acc.z + di2 * hd.z + b4.z;
  o.w = di * acc.w + di2 * hd.w + b4.w;
  if (apply_lrelu) {
    o.x = (o.x > 0.f) ? o.x : LRELU_SLOPE * o.x;
    o.y = (o.y > 0.f) ? o.y : LRELU_SLOPE * o.y;
    o.z = (o.z > 0.f) ? o.z : LRELU_SLOPE * o.z;
    o.w = (o.w > 0.f) ? o.w : LRELU_SLOPE * o.w;
  }
  *(float4*)(hout + (size_t)d * 64 + lane * 4) = o;
}

// ---------------- BN column stats: per-block partials (atomic-free) ----------------
__launch_bounds__(256)
__global__ void k_stats(const float* __restrict__ h, float* __restrict__ partial, int N) {
  __shared__ float ls[256], lss[256];
  const int t = threadIdx.x;
  const int c = t & 63;
  float a = 0.f, a2 = 0.f;
  for (int n = blockIdx.x * 4 + (t >> 6); n < N; n += gridDim.x * 4) {
    float v = h[(size_t)n * 64 + c];
    a += v;
    a2 += v * v;
  }
  ls[t] = a;
  lss[t] = a2;
  __syncthreads();
  if (t < 64) {
    a = ls[t] + ls[t + 64] + ls[t + 128] + ls[t + 192];
    a2 = lss[t] + lss[t + 64] + lss[t + 128] + lss[t + 192];
    partial[blockIdx.x * 128 + t] = a;
    partial[blockIdx.x * 128 + 64 + t] = a2;
  }
}

__global__ void k_stats_reduce(const float* __restrict__ partial, float* __restrict__ s,
                               float* __restrict__ ss, int nb) {
  int t = threadIdx.x;  // 128 threads
  float a = 0.f;
  for (int b = 0; b < nb; ++b) a += partial[b * 128 + t];
  if (t < 64) s[t] = a;
  else ss[t - 64] = a;
}

// ---------------- BN apply + LeakyReLU ----------------
__launch_bounds__(256)
__global__ void k_bnapply(const float* __restrict__ hin, float* __restrict__ hout,
                          const float* __restrict__ s, const float* __restrict__ ss,
                          const float* __restrict__ g, const float* __restrict__ be,
                          int N) {
  int i = blockIdx.x * blockDim.x + threadIdx.x;  // index over N*16 float4s
  if (i >= N * 16) return;
  int c0 = (i & 15) * 4;
  float invN = 1.0f / (float)N;
  float4 v = ((const float4*)hin)[i];
  float o[4] = {v.x, v.y, v.z, v.w};
#pragma unroll
  for (int k = 0; k < 4; ++k) {
    int c = c0 + k;
    float mean = s[c] * invN;
    float var = ss[c] * invN - mean * mean;
    float scale = g[c] * rsqrtf(var + BN_EPS);
    float r = (o[k] - mean) * scale + be[c];
    o[k] = (r > 0.f) ? r : LRELU_SLOPE * r;
  }
  ((float4*)hout)[i] = make_float4(o[0], o[1], o[2], o[3]);
}

// ---------------- graph boundaries from sorted batch (atomic-free) ----------------
__global__ void k_gbounds(const int* __restrict__ batch, int* __restrict__ gstart,
                          int N, int G) {
  int i = blockIdx.x * blockDim.x + threadIdx.x;
  if (i >= N) return;
  int b = batch[i];
  int prev = (i == 0) ? -1 : batch[i - 1];
  for (int g = prev + 1; g <= b; ++g) gstart[g] = i;   // batch sorted => prev <= b
  if (i == N - 1) {
    for (int g = b + 1; g <= G; ++g) gstart[g] = N;
  }
}

// ---------------- pooling (max & mean per graph) + FC, fused ----------------
__launch_bounds__(256)
__global__ void k_pool(const float* __restrict__ h, const int* __restrict__ gstart,
                       const float* __restrict__ Wfc, const float* __restrict__ bfc,
                       float* __restrict__ out, int G) {
  __shared__ float lmx[256], lsm[256], red[128];
  const int g = blockIdx.x;
  const int t = threadIdx.x;
  const int c = t & 63;
  const int sub = t >> 6;
  const int n0 = gstart[g];
  const int n1 = gstart[g + 1];
  float mx = -INFINITY, sm = 0.f;
  for (int n = n0 + sub; n < n1; n += 4) {
    float v = h[(size_t)n * 64 + c];
    mx = fmaxf(mx, v);
    sm += v;
  }
  lmx[t] = mx;
  lsm[t] = sm;
  __syncthreads();
  if (t < 64) {
    mx = fmaxf(fmaxf(lmx[t], lmx[t + 64]), fmaxf(lmx[t + 128], lmx[t + 192]));
    sm = lsm[t] + lsm[t + 64] + lsm[t + 128] + lsm[t + 192];
    float cntf = (float)(n1 - n0);
    float mean = sm / fmaxf(cntf, 1.0f);
    red[t] = mx * Wfc[t];
    red[t + 64] = mean * Wfc[64 + t];
  }
  __syncthreads();
  for (int st = 64; st >= 1; st >>= 1) {
    if (t < st) red[t] += red[t + st];
    __syncthreads();
  }
  if (t == 0) out[g] = red[0] + bfc[0];
}

// ---------------- host launch ----------------
extern "C" void kernel_launch(void* const* d_in, const int* in_sizes, int n_in,
                              void* d_out, int out_size, void* d_ws, size_t ws_size,
                              hipStream_t stream) {
  const float* x = (const float*)d_in[0];
  const int* ei = (const int*)d_in[1];
  const int* batch = (const int*)d_in[2];
  const float* eattr = (const float*)d_in[3];
  const float* W0 = (const float*)d_in[4];
  const float* b0 = (const float*)d_in[5];
  const float* g0 = (const float*)d_in[6];
  const float* be0 = (const float*)d_in[7];
  const float* W1 = (const float*)d_in[8];
  const float* b1 = (const float*)d_in[9];
  const float* g1 = (const float*)d_in[10];
  const float* be1 = (const float*)d_in[11];
  const float* W2 = (const float*)d_in[12];
  const float* b2 = (const float*)d_in[13];
  const float* W3 = (const float*)d_in[14];
  const float* b3 = (const float*)d_in[15];
  const float* Wfc = (const float*)d_in[16];
  const float* bfc = (const float*)d_in[17];
  float* out = (float*)d_out;

  const int N = in_sizes[2];       // batch is [N]
  const int E = in_sizes[3];       // edge_attr is [E]
  const int CIN = in_sizes[0] / N; // 128
  const int G = out_size;          // [G,1]

  // workspace carve-up (256B-aligned slices)
  size_t off = 0;
  auto alloc = [&](size_t bytes) -> void* {
    void* p = (char*)d_ws + off;
    off += (bytes + 255) & ~(size_t)255;
    return p;
  };
  unsigned long long* packed = (unsigned long long*)alloc((size_t)N * 8);
  float* dinv = (float*)alloc((size_t)N * 4);
  int* rowstart = (int*)alloc((size_t)(N + 1) * 4);
  int* fill = (int*)alloc((size_t)N * 4);
  int* bsum = (int*)alloc(1024 * 4);
  int* col = (int*)alloc((size_t)E * 4);
  float* val = (float*)alloc((size_t)E * 4);
  float* A = (float*)alloc((size_t)N * 64 * 4);
  float* B = (float*)alloc((size_t)N * 64 * 4);
  float* sums = (float*)alloc(256 * 4);   // s0|ss0|s1|ss1
  float* partial = (float*)alloc(256 * 128 * 4);
  int* gstart = (int*)alloc((size_t)(G + 1) * 4);
  (void)ws_size; (void)n_in; (void)CIN;

  const int nb = ceil_div(N, 1024);

  // graph structure (layer-invariant)
  k_init<<<ceil_div(N, 256), 256, 0, stream>>>(packed, fill, N);
  k_edge_count<<<ceil_div(E, 256), 256, 0, stream>>>(ei, eattr, packed, E);
  k_scan1<<<nb, 256, 0, stream>>>(packed, rowstart, bsum, N);
  k_scan2<<<1, 256, 0, stream>>>(bsum, nb);
  k_scan3<<<ceil_div(N + 1, 256), 256, 0, stream>>>(rowstart, bsum, packed, dinv, N, E);
  k_fill<<<ceil_div(E, 256), 256, 0, stream>>>(ei, eattr, rowstart, fill, dinv, col, val, E);
  k_gbounds<<<ceil_div(N, 256), 256, 0, stream>>>(batch, gstart, N, G);

  // layer 0: gemm(x,W0)->A; agg A->B; stats(B); bn+lrelu B->A
  k_gemm<128><<<ceil_div(N, 256), 256, 0, stream>>>(x, W0, A, N);
  k_agg<<<ceil_div(N, 16), 256, 0, stream>>>(A, B, b0, dinv, rowstart, col, val, N, 0);
  k_stats<<<256, 256, 0, stream>>>(B, partial, N);
  k_stats_reduce<<<1, 128, 0, stream>>>(partial, sums + 0, sums + 64, 256);
  k_bnapply<<<ceil_div(N * 16, 256), 256, 0, stream>>>(B, A, sums + 0, sums + 64, g0, be0, N);

  // layer 1: gemm(A,W1)->B; agg B->A; stats(A); bn+lrelu A->B
  k_gemm<64><<<ceil_div(N, 256), 256, 0, stream>>>(A, W1, B, N);
  k_agg<<<ceil_div(N, 16), 256, 0, stream>>>(B, A, b1, dinv, rowstart, col, val, N, 0);
  k_stats<<<256, 256, 0, stream>>>(A, partial, N);
  k_stats_reduce<<<1, 128, 0, stream>>>(partial, sums + 128, sums + 192, 256);
  k_bnapply<<<ceil_div(N * 16, 256), 256, 0, stream>>>(A, B, sums + 128, sums + 192, g1, be1, N);

  // layer 2: gemm(B,W2)->A; agg(+lrelu) A->B
  k_gemm<64><<<ceil_div(N, 256), 256, 0, stream>>>(B, W2, A, N);
  k_agg<<<ceil_div(N, 16), 256, 0, stream>>>(A, B, b2, dinv, rowstart, col, val, N, 1);

  // layer 3: gemm(B,W3)->A; agg(+lrelu) A->B
  k_gemm<64><<<ceil_div(N, 256), 256, 0, stream>>>(B, W3, A, N);
  k_agg<<<ceil_div(N, 16), 256, 0, stream>>>(A, B, b3, dinv, rowstart, col, val, N, 1);

  // pooling + FC
  k_pool<<<G, 256, 0, stream>>>(B, gstart, Wfc, bfc, out, G);
}

// Round 4
// 934.944 us; speedup vs baseline: 1.0632x; 1.0632x over previous
//
#include <hip/hip_runtime.h>
#include <math.h>

#define LRELU_SLOPE 0.01f
#define BN_EPS 1e-5f
#define DEG_SCALE 67108864.0f          /* 2^26 */
#define DEG_INV_SCALE 1.4901161e-8f    /* 2^-26 */
#define DEG_MASK 0xFFFFFFFFFFULL       /* low 40 bits */

static inline int ceil_div(int a, int b) { return (a + b - 1) / b; }

// ---------------- init: packed deg/cnt = (cnt=0, deg=1.0 fixed-point) ----------
__global__ void k_init(unsigned long long* __restrict__ packed, int N) {
  int i = blockIdx.x * blockDim.x + threadIdx.x;
  if (i < N) packed[i] = (unsigned long long)(1u << 26);
}

// ------- degree + per-dst edge count: ONE native u64 atomic per edge; keep rank -------
__global__ void k_edge_count(const int* __restrict__ ei, const float* __restrict__ w,
                             unsigned long long* __restrict__ packed,
                             int* __restrict__ rank, int E) {
  int e = blockIdx.x * blockDim.x + threadIdx.x;
  if (e >= E) return;
  int d = ei[E + e];            // dst row of edge_index
  unsigned int q = (unsigned int)__float2uint_rn(w[e] * DEG_SCALE);
  unsigned long long old = atomicAdd(&packed[d], (1ULL << 40) | (unsigned long long)q);
  rank[e] = (int)(old >> 40);   // this edge's position among same-dst edges
}

// ---------------- 2-level exclusive scan over edge counts (from packed) ----------------
__global__ void k_scan1(const unsigned long long* __restrict__ packed, int* __restrict__ out,
                        int* __restrict__ bsum, int n) {
  __shared__ int lds[256];
  const int t = threadIdx.x;
  const int base = blockIdx.x * 1024 + t * 4;
  int v0 = 0, v1 = 0, v2 = 0, v3 = 0;
  if (base + 0 < n) v0 = (int)(packed[base + 0] >> 40);
  if (base + 1 < n) v1 = (int)(packed[base + 1] >> 40);
  if (base + 2 < n) v2 = (int)(packed[base + 2] >> 40);
  if (base + 3 < n) v3 = (int)(packed[base + 3] >> 40);
  int s = v0 + v1 + v2 + v3;
  lds[t] = s;
  __syncthreads();
#pragma unroll
  for (int off = 1; off < 256; off <<= 1) {
    int y = 0;
    if (t >= off) y = lds[t - off];
    __syncthreads();
    if (t >= off) lds[t] += y;
    __syncthreads();
  }
  int incl = lds[t];
  int excl = incl - s;
  if (base + 0 < n) out[base + 0] = excl;
  if (base + 1 < n) out[base + 1] = excl + v0;
  if (base + 2 < n) out[base + 2] = excl + v0 + v1;
  if (base + 3 < n) out[base + 3] = excl + v0 + v1 + v2;
  if (t == 255) bsum[blockIdx.x] = incl;
}

__global__ void k_scan2(int* __restrict__ bsum, int nb) {  // in-place exclusive, nb<=256
  __shared__ int lds[256];
  int t = threadIdx.x;
  int v = (t < nb) ? bsum[t] : 0;
  lds[t] = v;
  __syncthreads();
#pragma unroll
  for (int off = 1; off < 256; off <<= 1) {
    int y = 0;
    if (t >= off) y = lds[t - off];
    __syncthreads();
    if (t >= off) lds[t] += y;
    __syncthreads();
  }
  if (t < nb) bsum[t] = lds[t] - v;
}

__global__ void k_scan3(int* __restrict__ rowstart, const int* __restrict__ bscan,
                        const unsigned long long* __restrict__ packed,
                        float* __restrict__ dinv, int N, int E) {
  int i = blockIdx.x * blockDim.x + threadIdx.x;
  if (i < N) {
    rowstart[i] += bscan[i >> 10];
    float d = (float)(packed[i] & DEG_MASK) * DEG_INV_SCALE;  // includes self-loop 1.0
    dinv[i] = (d > 0.0f) ? rsqrtf(d) : 0.0f;
  }
  if (i == N) rowstart[N] = E;
}

// -------- CSR fill (atomic-free): colval[p] = (src<<32)|bits(w*dinv[src]) --------
__global__ void k_fill(const int* __restrict__ ei, const float* __restrict__ w,
                       const int* __restrict__ rowstart, const int* __restrict__ rank,
                       const float* __restrict__ dinv,
                       unsigned long long* __restrict__ colval, int E) {
  int e = blockIdx.x * blockDim.x + threadIdx.x;
  if (e >= E) return;
  int s = ei[e];
  int d = ei[E + e];
  int p = rowstart[d] + rank[e];
  float v = w[e] * dinv[s];
  colval[p] = ((unsigned long long)(unsigned int)s << 32) |
              (unsigned long long)__float_as_uint(v);
}

// ---------------- GEMM: H[N,64] = X[N,K] @ W[K,64]  (fp32, VALU) ----------------
template <int K>
__launch_bounds__(256)
__global__ void k_gemm(const float* __restrict__ X, const float* __restrict__ W,
                       float* __restrict__ H, int N) {
  __shared__ float xl[256 * 33];
  const int t = threadIdx.x;
  const int node = blockIdx.x * 256 + t;
  float acc[64];
#pragma unroll
  for (int j = 0; j < 64; ++j) acc[j] = 0.0f;

  for (int kt = 0; kt < K; kt += 32) {
    __syncthreads();  // protect previous tile reads
#pragma unroll
    for (int l = 0; l < 8; ++l) {
      int row = (t >> 3) + l * 32;
      int kc = (t & 7) * 4;
      int gn = blockIdx.x * 256 + row;
      float4 v = make_float4(0.f, 0.f, 0.f, 0.f);
      if (gn < N) v = *(const float4*)(X + (size_t)gn * K + kt + kc);
      float* p = &xl[row * 33 + kc];
      p[0] = v.x; p[1] = v.y; p[2] = v.z; p[3] = v.w;
    }
    __syncthreads();
#pragma unroll 4
    for (int k = 0; k < 32; ++k) {
      float xv = xl[t * 33 + k];
      const float4* Wr = (const float4*)(W + (size_t)(kt + k) * 64);
#pragma unroll
      for (int j4 = 0; j4 < 16; ++j4) {
        float4 wv = Wr[j4];
        acc[4 * j4 + 0] += xv * wv.x;
        acc[4 * j4 + 1] += xv * wv.y;
        acc[4 * j4 + 2] += xv * wv.z;
        acc[4 * j4 + 3] += xv * wv.w;
      }
    }
  }
  if (node < N) {
#pragma unroll
    for (int j4 = 0; j4 < 16; ++j4) {
      float4 o = make_float4(acc[4 * j4 + 0], acc[4 * j4 + 1], acc[4 * j4 + 2], acc[4 * j4 + 3]);
      *(float4*)(H + (size_t)node * 64 + 4 * j4) = o;
    }
  }
}

// ---------------- CSR aggregation: out[d] = dinv[d]*sum(val*h[src]) + dinv[d]^2*h[d] + b ----
__launch_bounds__(256)
__global__ void k_agg(const float* __restrict__ hin, float* __restrict__ hout,
                      const float* __restrict__ bias, const float* __restrict__ dinv,
                      const int* __restrict__ rowstart,
                      const unsigned long long* __restrict__ colval,
                      int N, int apply_lrelu) {
  const int t = threadIdx.x;
  const int grp = t >> 4;
  const int lane = t & 15;
  const int d = blockIdx.x * 16 + grp;
  if (d >= N) return;
  const int r0 = rowstart[d];
  const int r1 = rowstart[d + 1];
  float4 acc = make_float4(0.f, 0.f, 0.f, 0.f);
  for (int r = r0; r < r1; ++r) {
    unsigned long long cv = colval[r];
    int s = (int)(cv >> 32);
    float v = __uint_as_float((unsigned int)cv);
    float4 hv = *(const float4*)(hin + (size_t)s * 64 + lane * 4);
    acc.x += v * hv.x;
    acc.y += v * hv.y;
    acc.z += v * hv.z;
    acc.w += v * hv.w;
  }
  float di = dinv[d];
  float di2 = di * di;
  float4 hd = *(const float4*)(hin + (size_t)d * 64 + lane * 4);
  float4 b4 = *(const float4*)(bias + lane * 4);
  float4 o;
  o.x = di * acc.x + di2 * hd.x + b4.x;
  o.y = di * acc.y + di2 * hd.y + b4.y;
  o.z = di * acc.z + di2 * hd.z + b4.z;
  o.w = di * acc.w + di2 * hd.w + b4.w;
  if (apply_lrelu) {
    o.x = (o.x > 0.f) ? o.x : LRELU_SLOPE * o.x;
    o.y = (o.y > 0.f) ? o.y : LRELU_SLOPE * o.y;
    o.z = (o.z > 0.f) ? o.z : LRELU_SLOPE * o.z;
    o.w = (o.w > 0.f) ? o.w : LRELU_SLOPE * o.w;
  }
  *(float4*)(hout + (size_t)d * 64 + lane * 4) = o;
}

// ---------------- BN column stats: per-block partials (atomic-free) ----------------
__launch_bounds__(256)
__global__ void k_stats(const float* __restrict__ h, float* __restrict__ partial, int N) {
  __shared__ float ls[256], lss[256];
  const int t = threadIdx.x;
  const int c = t & 63;
  float a = 0.f, a2 = 0.f;
  for (int n = blockIdx.x * 4 + (t >> 6); n < N; n += gridDim.x * 4) {
    float v = h[(size_t)n * 64 + c];
    a += v;
    a2 += v * v;
  }
  ls[t] = a;
  lss[t] = a2;
  __syncthreads();
  if (t < 64) {
    a = ls[t] + ls[t + 64] + ls[t + 128] + ls[t + 192];
    a2 = lss[t] + lss[t + 64] + lss[t + 128] + lss[t + 192];
    partial[blockIdx.x * 128 + t] = a;
    partial[blockIdx.x * 128 + 64 + t] = a2;
  }
}

__global__ void k_stats_reduce(const float* __restrict__ partial, float* __restrict__ s,
                               float* __restrict__ ss, int nb) {
  int t = threadIdx.x;  // 128 threads
  float a = 0.f;
  for (int b = 0; b < nb; ++b) a += partial[b * 128 + t];
  if (t < 64) s[t] = a;
  else ss[t - 64] = a;
}

// ---------------- BN apply + LeakyReLU ----------------
__launch_bounds__(256)
__global__ void k_bnapply(const float* __restrict__ hin, float* __restrict__ hout,
                          const float* __restrict__ s, const float* __restrict__ ss,
                          const float* __restrict__ g, const float* __restrict__ be,
                          int N) {
  int i = blockIdx.x * blockDim.x + threadIdx.x;  // index over N*16 float4s
  if (i >= N * 16) return;
  int c0 = (i & 15) * 4;
  float invN = 1.0f / (float)N;
  float4 v = ((const float4*)hin)[i];
  float o[4] = {v.x, v.y, v.z, v.w};
#pragma unroll
  for (int k = 0; k < 4; ++k) {
    int c = c0 + k;
    float mean = s[c] * invN;
    float var = ss[c] * invN - mean * mean;
    float scale = g[c] * rsqrtf(var + BN_EPS);
    float r = (o[k] - mean) * scale + be[c];
    o[k] = (r > 0.f) ? r : LRELU_SLOPE * r;
  }
  ((float4*)hout)[i] = make_float4(o[0], o[1], o[2], o[3]);
}

// ---------------- graph boundaries from sorted batch (atomic-free) ----------------
__global__ void k_gbounds(const int* __restrict__ batch, int* __restrict__ gstart,
                          int N, int G) {
  int i = blockIdx.x * blockDim.x + threadIdx.x;
  if (i >= N) return;
  int b = batch[i];
  int prev = (i == 0) ? -1 : batch[i - 1];
  for (int g = prev + 1; g <= b; ++g) gstart[g] = i;   // batch sorted => prev <= b
  if (i == N - 1) {
    for (int g = b + 1; g <= G; ++g) gstart[g] = N;
  }
}

// ---------------- pooling (max & mean per graph) + FC, fused ----------------
__launch_bounds__(256)
__global__ void k_pool(const float* __restrict__ h, const int* __restrict__ gstart,
                       const float* __restrict__ Wfc, const float* __restrict__ bfc,
                       float* __restrict__ out, int G) {
  __shared__ float lmx[256], lsm[256], red[128];
  const int g = blockIdx.x;
  const int t = threadIdx.x;
  const int c = t & 63;
  const int sub = t >> 6;
  const int n0 = gstart[g];
  const int n1 = gstart[g + 1];
  float mx = -INFINITY, sm = 0.f;
  for (int n = n0 + sub; n < n1; n += 4) {
    float v = h[(size_t)n * 64 + c];
    mx = fmaxf(mx, v);
    sm += v;
  }
  lmx[t] = mx;
  lsm[t] = sm;
  __syncthreads();
  if (t < 64) {
    mx = fmaxf(fmaxf(lmx[t], lmx[t + 64]), fmaxf(lmx[t + 128], lmx[t + 192]));
    sm = lsm[t] + lsm[t + 64] + lsm[t + 128] + lsm[t + 192];
    float cntf = (float)(n1 - n0);
    float mean = sm / fmaxf(cntf, 1.0f);
    red[t] = mx * Wfc[t];
    red[t + 64] = mean * Wfc[64 + t];
  }
  __syncthreads();
  for (int st = 64; st >= 1; st >>= 1) {
    if (t < st) red[t] += red[t + st];
    __syncthreads();
  }
  if (t == 0) out[g] = red[0] + bfc[0];
}

// ---------------- host launch ----------------
extern "C" void kernel_launch(void* const* d_in, const int* in_sizes, int n_in,
                              void* d_out, int out_size, void* d_ws, size_t ws_size,
                              hipStream_t stream) {
  const float* x = (const float*)d_in[0];
  const int* ei = (const int*)d_in[1];
  const int* batch = (const int*)d_in[2];
  const float* eattr = (const float*)d_in[3];
  const float* W0 = (const float*)d_in[4];
  const float* b0 = (const float*)d_in[5];
  const float* g0 = (const float*)d_in[6];
  const float* be0 = (const float*)d_in[7];
  const float* W1 = (const float*)d_in[8];
  const float* b1 = (const float*)d_in[9];
  const float* g1 = (const float*)d_in[10];
  const float* be1 = (const float*)d_in[11];
  const float* W2 = (const float*)d_in[12];
  const float* b2 = (const float*)d_in[13];
  const float* W3 = (const float*)d_in[14];
  const float* b3 = (const float*)d_in[15];
  const float* Wfc = (const float*)d_in[16];
  const float* bfc = (const float*)d_in[17];
  float* out = (float*)d_out;

  const int N = in_sizes[2];       // batch is [N]
  const int E = in_sizes[3];       // edge_attr is [E]
  const int CIN = in_sizes[0] / N; // 128
  const int G = out_size;          // [G,1]

  // workspace carve-up (256B-aligned slices)
  size_t off = 0;
  auto alloc = [&](size_t bytes) -> void* {
    void* p = (char*)d_ws + off;
    off += (bytes + 255) & ~(size_t)255;
    return p;
  };
  unsigned long long* packed = (unsigned long long*)alloc((size_t)N * 8);
  float* dinv = (float*)alloc((size_t)N * 4);
  int* rowstart = (int*)alloc((size_t)(N + 1) * 4);
  int* rank = (int*)alloc((size_t)E * 4);
  int* bsum = (int*)alloc(1024 * 4);
  unsigned long long* colval = (unsigned long long*)alloc((size_t)E * 8);
  float* A = (float*)alloc((size_t)N * 64 * 4);
  float* B = (float*)alloc((size_t)N * 64 * 4);
  float* sums = (float*)alloc(256 * 4);   // s0|ss0|s1|ss1
  float* partial = (float*)alloc(256 * 128 * 4);
  int* gstart = (int*)alloc((size_t)(G + 1) * 4);
  (void)ws_size; (void)n_in; (void)CIN;

  const int nb = ceil_div(N, 1024);

  // graph structure (layer-invariant)
  k_init<<<ceil_div(N, 256), 256, 0, stream>>>(packed, N);
  k_edge_count<<<ceil_div(E, 256), 256, 0, stream>>>(ei, eattr, packed, rank, E);
  k_scan1<<<nb, 256, 0, stream>>>(packed, rowstart, bsum, N);
  k_scan2<<<1, 256, 0, stream>>>(bsum, nb);
  k_scan3<<<ceil_div(N + 1, 256), 256, 0, stream>>>(rowstart, bsum, packed, dinv, N, E);
  k_fill<<<ceil_div(E, 256), 256, 0, stream>>>(ei, eattr, rowstart, rank, dinv, colval, E);
  k_gbounds<<<ceil_div(N, 256), 256, 0, stream>>>(batch, gstart, N, G);

  // layer 0: gemm(x,W0)->A; agg A->B; stats(B); bn+lrelu B->A
  k_gemm<128><<<ceil_div(N, 256), 256, 0, stream>>>(x, W0, A, N);
  k_agg<<<ceil_div(N, 16), 256, 0, stream>>>(A, B, b0, dinv, rowstart, colval, N, 0);
  k_stats<<<256, 256, 0, stream>>>(B, partial, N);
  k_stats_reduce<<<1, 128, 0, stream>>>(partial, sums + 0, sums + 64, 256);
  k_bnapply<<<ceil_div(N * 16, 256), 256, 0, stream>>>(B, A, sums + 0, sums + 64, g0, be0, N);

  // layer 1: gemm(A,W1)->B; agg B->A; stats(A); bn+lrelu A->B
  k_gemm<64><<<ceil_div(N, 256), 256, 0, stream>>>(A, W1, B, N);
  k_agg<<<ceil_div(N, 16), 256, 0, stream>>>(B, A, b1, dinv, rowstart, colval, N, 0);
  k_stats<<<256, 256, 0, stream>>>(A, partial, N);
  k_stats_reduce<<<1, 128, 0, stream>>>(partial, sums + 128, sums + 192, 256);
  k_bnapply<<<ceil_div(N * 16, 256), 256, 0, stream>>>(A, B, sums + 128, sums + 192, g1, be1, N);

  // layer 2: gemm(B,W2)->A; agg(+lrelu) A->B
  k_gemm<64><<<ceil_div(N, 256), 256, 0, stream>>>(B, W2, A, N);
  k_agg<<<ceil_div(N, 16), 256, 0, stream>>>(A, B, b2, dinv, rowstart, colval, N, 1);

  // layer 3: gemm(B,W3)->A; agg(+lrelu) A->B
  k_gemm<64><<<ceil_div(N, 256), 256, 0, stream>>>(B, W3, A, N);
  k_agg<<<ceil_div(N, 16), 256, 0, stream>>>(A, B, b3, dinv, rowstart, colval, N, 1);

  // pooling + FC
  k_pool<<<G, 256, 0, stream>>>(B, gstart, Wfc, bfc, out, G);
}

// Round 5
// 905.565 us; speedup vs baseline: 1.0977x; 1.0324x over previous
//
#include <hip/hip_runtime.h>
#include <math.h>

#define LRELU_SLOPE 0.01f
#define BN_EPS 1e-5f
#define DEG_SCALE 67108864.0f          /* 2^26 */
#define DEG_INV_SCALE 1.4901161e-8f    /* 2^-26 */
#define DEG_MASK 0xFFFFFFFFFFULL       /* low 40 bits */

static inline int ceil_div(int a, int b) { return (a + b - 1) / b; }

// ---------------- init: packed deg/cnt = (cnt=0, deg=1.0 fixed-point) ----------
__global__ void k_init(unsigned long long* __restrict__ packed, int N) {
  int i = blockIdx.x * blockDim.x + threadIdx.x;
  if (i < N) packed[i] = (unsigned long long)(1u << 26);
}

// ------- degree + per-dst edge count: ONE native u64 atomic per edge; keep rank -------
// 4 edges/thread (strided) => 4 independent returning atomics in flight per lane.
__global__ void k_edge_count(const int* __restrict__ ei, const float* __restrict__ w,
                             unsigned long long* __restrict__ packed,
                             int* __restrict__ rank, int E) {
  const int base = blockIdx.x * (blockDim.x * 4) + threadIdx.x;
  int e0 = base, e1 = base + 256, e2 = base + 512, e3 = base + 768;
  unsigned long long r0 = 0, r1 = 0, r2 = 0, r3 = 0;
  if (e0 < E) {
    int d = ei[E + e0];
    unsigned int q = (unsigned int)__float2uint_rn(w[e0] * DEG_SCALE);
    r0 = atomicAdd(&packed[d], (1ULL << 40) | (unsigned long long)q);
  }
  if (e1 < E) {
    int d = ei[E + e1];
    unsigned int q = (unsigned int)__float2uint_rn(w[e1] * DEG_SCALE);
    r1 = atomicAdd(&packed[d], (1ULL << 40) | (unsigned long long)q);
  }
  if (e2 < E) {
    int d = ei[E + e2];
    unsigned int q = (unsigned int)__float2uint_rn(w[e2] * DEG_SCALE);
    r2 = atomicAdd(&packed[d], (1ULL << 40) | (unsigned long long)q);
  }
  if (e3 < E) {
    int d = ei[E + e3];
    unsigned int q = (unsigned int)__float2uint_rn(w[e3] * DEG_SCALE);
    r3 = atomicAdd(&packed[d], (1ULL << 40) | (unsigned long long)q);
  }
  if (e0 < E) rank[e0] = (int)(r0 >> 40);
  if (e1 < E) rank[e1] = (int)(r1 >> 40);
  if (e2 < E) rank[e2] = (int)(r2 >> 40);
  if (e3 < E) rank[e3] = (int)(r3 >> 40);
}

// ---------------- 2-level exclusive scan over edge counts (from packed) ----------------
__global__ void k_scan1(const unsigned long long* __restrict__ packed, int* __restrict__ out,
                        int* __restrict__ bsum, int n) {
  __shared__ int lds[256];
  const int t = threadIdx.x;
  const int base = blockIdx.x * 1024 + t * 4;
  int v0 = 0, v1 = 0, v2 = 0, v3 = 0;
  if (base + 0 < n) v0 = (int)(packed[base + 0] >> 40);
  if (base + 1 < n) v1 = (int)(packed[base + 1] >> 40);
  if (base + 2 < n) v2 = (int)(packed[base + 2] >> 40);
  if (base + 3 < n) v3 = (int)(packed[base + 3] >> 40);
  int s = v0 + v1 + v2 + v3;
  lds[t] = s;
  __syncthreads();
#pragma unroll
  for (int off = 1; off < 256; off <<= 1) {
    int y = 0;
    if (t >= off) y = lds[t - off];
    __syncthreads();
    if (t >= off) lds[t] += y;
    __syncthreads();
  }
  int incl = lds[t];
  int excl = incl - s;
  if (base + 0 < n) out[base + 0] = excl;
  if (base + 1 < n) out[base + 1] = excl + v0;
  if (base + 2 < n) out[base + 2] = excl + v0 + v1;
  if (base + 3 < n) out[base + 3] = excl + v0 + v1 + v2;
  if (t == 255) bsum[blockIdx.x] = incl;
}

__global__ void k_scan2(int* __restrict__ bsum, int nb) {  // in-place exclusive, nb<=256
  __shared__ int lds[256];
  int t = threadIdx.x;
  int v = (t < nb) ? bsum[t] : 0;
  lds[t] = v;
  __syncthreads();
#pragma unroll
  for (int off = 1; off < 256; off <<= 1) {
    int y = 0;
    if (t >= off) y = lds[t - off];
    __syncthreads();
    if (t >= off) lds[t] += y;
    __syncthreads();
  }
  if (t < nb) bsum[t] = lds[t] - v;
}

__global__ void k_scan3(int* __restrict__ rowstart, const int* __restrict__ bscan,
                        const unsigned long long* __restrict__ packed,
                        float* __restrict__ dinv, int N, int E) {
  int i = blockIdx.x * blockDim.x + threadIdx.x;
  if (i < N) {
    rowstart[i] += bscan[i >> 10];
    float d = (float)(packed[i] & DEG_MASK) * DEG_INV_SCALE;  // includes self-loop 1.0
    dinv[i] = (d > 0.0f) ? rsqrtf(d) : 0.0f;
  }
  if (i == N) rowstart[N] = E;
}

// -------- CSR fill (atomic-free): colval[p] = (src<<32)|bits(w*dinv[src]) --------
__global__ void k_fill(const int* __restrict__ ei, const float* __restrict__ w,
                       const int* __restrict__ rowstart, const int* __restrict__ rank,
                       const float* __restrict__ dinv,
                       unsigned long long* __restrict__ colval, int E) {
  int e = blockIdx.x * blockDim.x + threadIdx.x;
  if (e >= E) return;
  int s = ei[e];
  int d = ei[E + e];
  int p = rowstart[d] + rank[e];
  float v = w[e] * dinv[s];
  colval[p] = ((unsigned long long)(unsigned int)s << 32) |
              (unsigned long long)__float_as_uint(v);
}

// ---------------- GEMM: H[N,64] = X[N,K] @ W[K,64]  (fp32, VALU) ----------------
// __launch_bounds__(256,1): lift VGPR cap so the 64-float accumulator stays in
// registers (default heuristic capped at 56 VGPR -> spilled accs -> 80us/launch).
template <int K>
__launch_bounds__(256, 1)
__global__ void k_gemm(const float* __restrict__ X, const float* __restrict__ W,
                       float* __restrict__ H, int N) {
  __shared__ float xl[256 * 33];
  const int t = threadIdx.x;
  const int node = blockIdx.x * 256 + t;
  float acc[64];
#pragma unroll
  for (int j = 0; j < 64; ++j) acc[j] = 0.0f;

  for (int kt = 0; kt < K; kt += 32) {
    __syncthreads();  // protect previous tile reads
#pragma unroll
    for (int l = 0; l < 8; ++l) {
      int row = (t >> 3) + l * 32;
      int kc = (t & 7) * 4;
      int gn = blockIdx.x * 256 + row;
      float4 v = make_float4(0.f, 0.f, 0.f, 0.f);
      if (gn < N) v = *(const float4*)(X + (size_t)gn * K + kt + kc);
      float* p = &xl[row * 33 + kc];
      p[0] = v.x; p[1] = v.y; p[2] = v.z; p[3] = v.w;
    }
    __syncthreads();
#pragma unroll 4
    for (int k = 0; k < 32; ++k) {
      float xv = xl[t * 33 + k];
      const float4* Wr = (const float4*)(W + (size_t)(kt + k) * 64);
#pragma unroll
      for (int j4 = 0; j4 < 16; ++j4) {
        float4 wv = Wr[j4];
        acc[4 * j4 + 0] += xv * wv.x;
        acc[4 * j4 + 1] += xv * wv.y;
        acc[4 * j4 + 2] += xv * wv.z;
        acc[4 * j4 + 3] += xv * wv.w;
      }
    }
  }
  if (node < N) {
#pragma unroll
    for (int j4 = 0; j4 < 16; ++j4) {
      float4 o = make_float4(acc[4 * j4 + 0], acc[4 * j4 + 1], acc[4 * j4 + 2], acc[4 * j4 + 3]);
      *(float4*)(H + (size_t)node * 64 + 4 * j4) = o;
    }
  }
}

// ---------------- CSR aggregation: out[d] = dinv[d]*sum(val*h[src]) + dinv[d]^2*h[d] + b ----
__launch_bounds__(256)
__global__ void k_agg(const float* __restrict__ hin, float* __restrict__ hout,
                      const float* __restrict__ bias, const float* __restrict__ dinv,
                      const int* __restrict__ rowstart,
                      const unsigned long long* __restrict__ colval,
                      int N, int apply_lrelu) {
  const int t = threadIdx.x;
  const int grp = t >> 4;
  const int lane = t & 15;
  const int d = blockIdx.x * 16 + grp;
  if (d >= N) return;
  const int r0 = rowstart[d];
  const int r1 = rowstart[d + 1];
  float4 acc = make_float4(0.f, 0.f, 0.f, 0.f);
  for (int r = r0; r < r1; ++r) {
    unsigned long long cv = colval[r];
    int s = (int)(cv >> 32);
    float v = __uint_as_float((unsigned int)cv);
    float4 hv = *(const float4*)(hin + (size_t)s * 64 + lane * 4);
    acc.x += v * hv.x;
    acc.y += v * hv.y;
    acc.z += v * hv.z;
    acc.w += v * hv.w;
  }
  float di = dinv[d];
  float di2 = di * di;
  float4 hd = *(const float4*)(hin + (size_t)d * 64 + lane * 4);
  float4 b4 = *(const float4*)(bias + lane * 4);
  float4 o;
  o.x = di * acc.x + di2 * hd.x + b4.x;
  o.y = di * acc.y + di2 * hd.y + b4.y;
  o.z = di * acc.z + di2 * hd.z + b4.z;
  o.w = di * acc.w + di2 * hd.w + b4.w;
  if (apply_lrelu) {
    o.x = (o.x > 0.f) ? o.x : LRELU_SLOPE * o.x;
    o.y = (o.y > 0.f) ? o.y : LRELU_SLOPE * o.y;
    o.z = (o.z > 0.f) ? o.z : LRELU_SLOPE * o.z;
    o.w = (o.w > 0.f) ? o.w : LRELU_SLOPE * o.w;
  }
  *(float4*)(hout + (size_t)d * 64 + lane * 4) = o;
}

// ---------------- BN column stats: per-block partials (atomic-free) ----------------
__launch_bounds__(256)
__global__ void k_stats(const float* __restrict__ h, float* __restrict__ partial, int N) {
  __shared__ float ls[256], lss[256];
  const int t = threadIdx.x;
  const int c = t & 63;
  float a = 0.f, a2 = 0.f;
  for (int n = blockIdx.x * 4 + (t >> 6); n < N; n += gridDim.x * 4) {
    float v = h[(size_t)n * 64 + c];
    a += v;
    a2 += v * v;
  }
  ls[t] = a;
  lss[t] = a2;
  __syncthreads();
  if (t < 64) {
    a = ls[t] + ls[t + 64] + ls[t + 128] + ls[t + 192];
    a2 = lss[t] + lss[t + 64] + lss[t + 128] + lss[t + 192];
    partial[blockIdx.x * 128 + t] = a;
    partial[blockIdx.x * 128 + 64 + t] = a2;
  }
}

__global__ void k_stats_reduce(const float* __restrict__ partial, float* __restrict__ s,
                               float* __restrict__ ss, int nb) {
  int t = threadIdx.x;  // 128 threads
  float a = 0.f;
  for (int b = 0; b < nb; ++b) a += partial[b * 128 + t];
  if (t < 64) s[t] = a;
  else ss[t - 64] = a;
}

// ---------------- BN apply + LeakyReLU ----------------
__launch_bounds__(256)
__global__ void k_bnapply(const float* __restrict__ hin, float* __restrict__ hout,
                          const float* __restrict__ s, const float* __restrict__ ss,
                          const float* __restrict__ g, const float* __restrict__ be,
                          int N) {
  int i = blockIdx.x * blockDim.x + threadIdx.x;  // index over N*16 float4s
  if (i >= N * 16) return;
  int c0 = (i & 15) * 4;
  float invN = 1.0f / (float)N;
  float4 v = ((const float4*)hin)[i];
  float o[4] = {v.x, v.y, v.z, v.w};
#pragma unroll
  for (int k = 0; k < 4; ++k) {
    int c = c0 + k;
    float mean = s[c] * invN;
    float var = ss[c] * invN - mean * mean;
    float scale = g[c] * rsqrtf(var + BN_EPS);
    float r = (o[k] - mean) * scale + be[c];
    o[k] = (r > 0.f) ? r : LRELU_SLOPE * r;
  }
  ((float4*)hout)[i] = make_float4(o[0], o[1], o[2], o[3]);
}

// ---------------- graph boundaries from sorted batch (atomic-free) ----------------
__global__ void k_gbounds(const int* __restrict__ batch, int* __restrict__ gstart,
                          int N, int G) {
  int i = blockIdx.x * blockDim.x + threadIdx.x;
  if (i >= N) return;
  int b = batch[i];
  int prev = (i == 0) ? -1 : batch[i - 1];
  for (int g = prev + 1; g <= b; ++g) gstart[g] = i;   // batch sorted => prev <= b
  if (i == N - 1) {
    for (int g = b + 1; g <= G; ++g) gstart[g] = N;
  }
}

// ---------------- pooling (max & mean per graph) + FC, fused ----------------
__launch_bounds__(256)
__global__ void k_pool(const float* __restrict__ h, const int* __restrict__ gstart,
                       const float* __restrict__ Wfc, const float* __restrict__ bfc,
                       float* __restrict__ out, int G) {
  __shared__ float lmx[256], lsm[256], red[128];
  const int g = blockIdx.x;
  const int t = threadIdx.x;
  const int c = t & 63;
  const int sub = t >> 6;
  const int n0 = gstart[g];
  const int n1 = gstart[g + 1];
  float mx = -INFINITY, sm = 0.f;
  for (int n = n0 + sub; n < n1; n += 4) {
    float v = h[(size_t)n * 64 + c];
    mx = fmaxf(mx, v);
    sm += v;
  }
  lmx[t] = mx;
  lsm[t] = sm;
  __syncthreads();
  if (t < 64) {
    mx = fmaxf(fmaxf(lmx[t], lmx[t + 64]), fmaxf(lmx[t + 128], lmx[t + 192]));
    sm = lsm[t] + lsm[t + 64] + lsm[t + 128] + lsm[t + 192];
    float cntf = (float)(n1 - n0);
    float mean = sm / fmaxf(cntf, 1.0f);
    red[t] = mx * Wfc[t];
    red[t + 64] = mean * Wfc[64 + t];
  }
  __syncthreads();
  for (int st = 64; st >= 1; st >>= 1) {
    if (t < st) red[t] += red[t + st];
    __syncthreads();
  }
  if (t == 0) out[g] = red[0] + bfc[0];
}

// ---------------- host launch ----------------
extern "C" void kernel_launch(void* const* d_in, const int* in_sizes, int n_in,
                              void* d_out, int out_size, void* d_ws, size_t ws_size,
                              hipStream_t stream) {
  const float* x = (const float*)d_in[0];
  const int* ei = (const int*)d_in[1];
  const int* batch = (const int*)d_in[2];
  const float* eattr = (const float*)d_in[3];
  const float* W0 = (const float*)d_in[4];
  const float* b0 = (const float*)d_in[5];
  const float* g0 = (const float*)d_in[6];
  const float* be0 = (const float*)d_in[7];
  const float* W1 = (const float*)d_in[8];
  const float* b1 = (const float*)d_in[9];
  const float* g1 = (const float*)d_in[10];
  const float* be1 = (const float*)d_in[11];
  const float* W2 = (const float*)d_in[12];
  const float* b2 = (const float*)d_in[13];
  const float* W3 = (const float*)d_in[14];
  const float* b3 = (const float*)d_in[15];
  const float* Wfc = (const float*)d_in[16];
  const float* bfc = (const float*)d_in[17];
  float* out = (float*)d_out;

  const int N = in_sizes[2];       // batch is [N]
  const int E = in_sizes[3];       // edge_attr is [E]
  const int CIN = in_sizes[0] / N; // 128
  const int G = out_size;          // [G,1]

  // workspace carve-up (256B-aligned slices)
  size_t off = 0;
  auto alloc = [&](size_t bytes) -> void* {
    void* p = (char*)d_ws + off;
    off += (bytes + 255) & ~(size_t)255;
    return p;
  };
  unsigned long long* packed = (unsigned long long*)alloc((size_t)N * 8);
  float* dinv = (float*)alloc((size_t)N * 4);
  int* rowstart = (int*)alloc((size_t)(N + 1) * 4);
  int* rank = (int*)alloc((size_t)E * 4);
  int* bsum = (int*)alloc(1024 * 4);
  unsigned long long* colval = (unsigned long long*)alloc((size_t)E * 8);
  float* A = (float*)alloc((size_t)N * 64 * 4);
  float* B = (float*)alloc((size_t)N * 64 * 4);
  float* sums = (float*)alloc(256 * 4);   // s0|ss0|s1|ss1
  float* partial = (float*)alloc(256 * 128 * 4);
  int* gstart = (int*)alloc((size_t)(G + 1) * 4);
  (void)ws_size; (void)n_in; (void)CIN;

  const int nb = ceil_div(N, 1024);

  // graph structure (layer-invariant)
  k_init<<<ceil_div(N, 256), 256, 0, stream>>>(packed, N);
  k_edge_count<<<ceil_div(E, 1024), 256, 0, stream>>>(ei, eattr, packed, rank, E);
  k_scan1<<<nb, 256, 0, stream>>>(packed, rowstart, bsum, N);
  k_scan2<<<1, 256, 0, stream>>>(bsum, nb);
  k_scan3<<<ceil_div(N + 1, 256), 256, 0, stream>>>(rowstart, bsum, packed, dinv, N, E);
  k_fill<<<ceil_div(E, 256), 256, 0, stream>>>(ei, eattr, rowstart, rank, dinv, colval, E);
  k_gbounds<<<ceil_div(N, 256), 256, 0, stream>>>(batch, gstart, N, G);

  // layer 0: gemm(x,W0)->A; agg A->B; stats(B); bn+lrelu B->A
  k_gemm<128><<<ceil_div(N, 256), 256, 0, stream>>>(x, W0, A, N);
  k_agg<<<ceil_div(N, 16), 256, 0, stream>>>(A, B, b0, dinv, rowstart, colval, N, 0);
  k_stats<<<256, 256, 0, stream>>>(B, partial, N);
  k_stats_reduce<<<1, 128, 0, stream>>>(partial, sums + 0, sums + 64, 256);
  k_bnapply<<<ceil_div(N * 16, 256), 256, 0, stream>>>(B, A, sums + 0, sums + 64, g0, be0, N);

  // layer 1: gemm(A,W1)->B; agg B->A; stats(A); bn+lrelu A->B
  k_gemm<64><<<ceil_div(N, 256), 256, 0, stream>>>(A, W1, B, N);
  k_agg<<<ceil_div(N, 16), 256, 0, stream>>>(B, A, b1, dinv, rowstart, colval, N, 0);
  k_stats<<<256, 256, 0, stream>>>(A, partial, N);
  k_stats_reduce<<<1, 128, 0, stream>>>(partial, sums + 128, sums + 192, 256);
  k_bnapply<<<ceil_div(N * 16, 256), 256, 0, stream>>>(A, B, sums + 128, sums + 192, g1, be1, N);

  // layer 2: gemm(B,W2)->A; agg(+lrelu) A->B
  k_gemm<64><<<ceil_div(N, 256), 256, 0, stream>>>(B, W2, A, N);
  k_agg<<<ceil_div(N, 16), 256, 0, stream>>>(A, B, b2, dinv, rowstart, colval, N, 1);

  // layer 3: gemm(B,W3)->A; agg(+lrelu) A->B
  k_gemm<64><<<ceil_div(N, 256), 256, 0, stream>>>(B, W3, A, N);
  k_agg<<<ceil_div(N, 16), 256, 0, stream>>>(A, B, b3, dinv, rowstart, colval, N, 1);

  // pooling + FC
  k_pool<<<G, 256, 0, stream>>>(B, gstart, Wfc, bfc, out, G);
}

// Round 6
// 818.408 us; speedup vs baseline: 1.2146x; 1.1065x over previous
//
#include <hip/hip_runtime.h>
#include <math.h>

#define LRELU_SLOPE 0.01f
#define BN_EPS 1e-5f
#define DEG_SCALE 67108864.0f          /* 2^26 */
#define DEG_INV_SCALE 1.4901161e-8f    /* 2^-26 */
#define DEG_MASK 0xFFFFFFFFFFULL       /* low 40 bits */

static inline int ceil_div(int a, int b) { return (a + b - 1) / b; }

// ---------------- init: packed deg/cnt = (cnt=0, deg=1.0 fixed-point) ----------
__global__ void k_init(unsigned long long* __restrict__ packed, int N) {
  int i = blockIdx.x * blockDim.x + threadIdx.x;
  if (i < N) packed[i] = (unsigned long long)(1u << 26);
}

// ------- degree + per-dst edge count: ONE native u64 atomic per edge; keep rank -------
__global__ void k_edge_count(const int* __restrict__ ei, const float* __restrict__ w,
                             unsigned long long* __restrict__ packed,
                             int* __restrict__ rank, int E) {
  const int base = blockIdx.x * (blockDim.x * 4) + threadIdx.x;
  int e0 = base, e1 = base + 256, e2 = base + 512, e3 = base + 768;
  unsigned long long r0 = 0, r1 = 0, r2 = 0, r3 = 0;
  if (e0 < E) {
    int d = ei[E + e0];
    unsigned int q = (unsigned int)__float2uint_rn(w[e0] * DEG_SCALE);
    r0 = atomicAdd(&packed[d], (1ULL << 40) | (unsigned long long)q);
  }
  if (e1 < E) {
    int d = ei[E + e1];
    unsigned int q = (unsigned int)__float2uint_rn(w[e1] * DEG_SCALE);
    r1 = atomicAdd(&packed[d], (1ULL << 40) | (unsigned long long)q);
  }
  if (e2 < E) {
    int d = ei[E + e2];
    unsigned int q = (unsigned int)__float2uint_rn(w[e2] * DEG_SCALE);
    r2 = atomicAdd(&packed[d], (1ULL << 40) | (unsigned long long)q);
  }
  if (e3 < E) {
    int d = ei[E + e3];
    unsigned int q = (unsigned int)__float2uint_rn(w[e3] * DEG_SCALE);
    r3 = atomicAdd(&packed[d], (1ULL << 40) | (unsigned long long)q);
  }
  if (e0 < E) rank[e0] = (int)(r0 >> 40);
  if (e1 < E) rank[e1] = (int)(r1 >> 40);
  if (e2 < E) rank[e2] = (int)(r2 >> 40);
  if (e3 < E) rank[e3] = (int)(r3 >> 40);
}

// ---------------- 2-level exclusive scan over edge counts (from packed) ----------------
__global__ void k_scan1(const unsigned long long* __restrict__ packed, int* __restrict__ out,
                        int* __restrict__ bsum, int n) {
  __shared__ int lds[256];
  const int t = threadIdx.x;
  const int base = blockIdx.x * 1024 + t * 4;
  int v0 = 0, v1 = 0, v2 = 0, v3 = 0;
  if (base + 0 < n) v0 = (int)(packed[base + 0] >> 40);
  if (base + 1 < n) v1 = (int)(packed[base + 1] >> 40);
  if (base + 2 < n) v2 = (int)(packed[base + 2] >> 40);
  if (base + 3 < n) v3 = (int)(packed[base + 3] >> 40);
  int s = v0 + v1 + v2 + v3;
  lds[t] = s;
  __syncthreads();
#pragma unroll
  for (int off = 1; off < 256; off <<= 1) {
    int y = 0;
    if (t >= off) y = lds[t - off];
    __syncthreads();
    if (t >= off) lds[t] += y;
    __syncthreads();
  }
  int incl = lds[t];
  int excl = incl - s;
  if (base + 0 < n) out[base + 0] = excl;
  if (base + 1 < n) out[base + 1] = excl + v0;
  if (base + 2 < n) out[base + 2] = excl + v0 + v1;
  if (base + 3 < n) out[base + 3] = excl + v0 + v1 + v2;
  if (t == 255) bsum[blockIdx.x] = incl;
}

__global__ void k_scan2(int* __restrict__ bsum, int nb) {  // in-place exclusive, nb<=256
  __shared__ int lds[256];
  int t = threadIdx.x;
  int v = (t < nb) ? bsum[t] : 0;
  lds[t] = v;
  __syncthreads();
#pragma unroll
  for (int off = 1; off < 256; off <<= 1) {
    int y = 0;
    if (t >= off) y = lds[t - off];
    __syncthreads();
    if (t >= off) lds[t] += y;
    __syncthreads();
  }
  if (t < nb) bsum[t] = lds[t] - v;
}

__global__ void k_scan3(int* __restrict__ rowstart, const int* __restrict__ bscan,
                        const unsigned long long* __restrict__ packed,
                        float* __restrict__ dinv, int N, int E) {
  int i = blockIdx.x * blockDim.x + threadIdx.x;
  if (i < N) {
    rowstart[i] += bscan[i >> 10];
    float d = (float)(packed[i] & DEG_MASK) * DEG_INV_SCALE;  // includes self-loop 1.0
    dinv[i] = (d > 0.0f) ? rsqrtf(d) : 0.0f;
  }
  if (i == N) rowstart[N] = E;
}

// -------- CSR fill (atomic-free): colval[p] = (src<<32)|bits(w*dinv[src]) --------
__global__ void k_fill(const int* __restrict__ ei, const float* __restrict__ w,
                       const int* __restrict__ rowstart, const int* __restrict__ rank,
                       const float* __restrict__ dinv,
                       unsigned long long* __restrict__ colval, int E) {
  int e = blockIdx.x * blockDim.x + threadIdx.x;
  if (e >= E) return;
  int s = ei[e];
  int d = ei[E + e];
  int p = rowstart[d] + rank[e];
  float v = w[e] * dinv[s];
  colval[p] = ((unsigned long long)(unsigned int)s << 32) |
              (unsigned long long)__float_as_uint(v);
}

// ---------------- GEMM: H[N,64] = X[N,K] @ W[K,64]  (fp32, VALU) ----------------
// Register-blocked: 256 threads (16x16), block tile 64 nodes x 64 cols, each
// thread a 4x4 accumulator (16 VGPRs -- round 4/5 showed a 64-float acc array
// never stays in arch VGPRs regardless of __launch_bounds__). X staged
// transposed [k][node] (pad 68, aligned b128 broadcast reads); W staged
// [k][col] (b128 reads, 2-way bank aliasing = free).
template <int K>
__launch_bounds__(256, 4)
__global__ void k_gemm(const float* __restrict__ X, const float* __restrict__ W,
                       float* __restrict__ H, int N) {
  __shared__ float Xl[64 * 68];
  __shared__ float Wl[64 * 64];
  const int t = threadIdx.x;
  const int tx = t & 15;
  const int ty = t >> 4;
  const int n0 = blockIdx.x * 64;

  float4 acc[4];
#pragma unroll
  for (int r = 0; r < 4; ++r) acc[r] = make_float4(0.f, 0.f, 0.f, 0.f);

  for (int kt = 0; kt < K; kt += 64) {
    __syncthreads();  // protect previous tile reads
    // stage X tile (64 nodes x 64 k), transposed into Xl[k][node]
#pragma unroll
    for (int l = 0; l < 4; ++l) {
      int idx = t + l * 256;          // float4 index 0..1023
      int node = idx >> 4;            // 16 float4 per node row
      int kq = idx & 15;
      int gn = n0 + node;
      float4 v = make_float4(0.f, 0.f, 0.f, 0.f);
      if (gn < N) v = *(const float4*)(X + (size_t)gn * K + kt + 4 * kq);
      int kb = 4 * kq;
      Xl[(kb + 0) * 68 + node] = v.x;
      Xl[(kb + 1) * 68 + node] = v.y;
      Xl[(kb + 2) * 68 + node] = v.z;
      Xl[(kb + 3) * 68 + node] = v.w;
    }
    // stage W tile (64 k x 64 cols), direct copy
#pragma unroll
    for (int l = 0; l < 4; ++l) {
      int idx = t + l * 256;          // float4 index over 64*16
      ((float4*)Wl)[idx] = *(const float4*)(W + (size_t)(kt + (idx >> 4)) * 64 + 4 * (idx & 15));
    }
    __syncthreads();
#pragma unroll 8
    for (int k = 0; k < 64; ++k) {
      float4 xv = *(const float4*)(Xl + k * 68 + 4 * ty);
      float4 wv = *(const float4*)(Wl + k * 64 + 4 * tx);
      acc[0].x += xv.x * wv.x; acc[0].y += xv.x * wv.y; acc[0].z += xv.x * wv.z; acc[0].w += xv.x * wv.w;
      acc[1].x += xv.y * wv.x; acc[1].y += xv.y * wv.y; acc[1].z += xv.y * wv.z; acc[1].w += xv.y * wv.w;
      acc[2].x += xv.z * wv.x; acc[2].y += xv.z * wv.y; acc[2].z += xv.z * wv.z; acc[2].w += xv.z * wv.w;
      acc[3].x += xv.w * wv.x; acc[3].y += xv.w * wv.y; acc[3].z += xv.w * wv.z; acc[3].w += xv.w * wv.w;
    }
  }
#pragma unroll
  for (int r = 0; r < 4; ++r) {
    int gn = n0 + 4 * ty + r;
    if (gn < N) *(float4*)(H + (size_t)gn * 64 + 4 * tx) = acc[r];
  }
}

// ---------------- CSR aggregation: out[d] = dinv[d]*sum(val*h[src]) + dinv[d]^2*h[d] + b ----
__launch_bounds__(256)
__global__ void k_agg(const float* __restrict__ hin, float* __restrict__ hout,
                      const float* __restrict__ bias, const float* __restrict__ dinv,
                      const int* __restrict__ rowstart,
                      const unsigned long long* __restrict__ colval,
                      int N, int apply_lrelu) {
  const int t = threadIdx.x;
  const int grp = t >> 4;
  const int lane = t & 15;
  const int d = blockIdx.x * 16 + grp;
  if (d >= N) return;
  const int r0 = rowstart[d];
  const int r1 = rowstart[d + 1];
  float4 acc = make_float4(0.f, 0.f, 0.f, 0.f);
  for (int r = r0; r < r1; ++r) {
    unsigned long long cv = colval[r];
    int s = (int)(cv >> 32);
    float v = __uint_as_float((unsigned int)cv);
    float4 hv = *(const float4*)(hin + (size_t)s * 64 + lane * 4);
    acc.x += v * hv.x;
    acc.y += v * hv.y;
    acc.z += v * hv.z;
    acc.w += v * hv.w;
  }
  float di = dinv[d];
  float di2 = di * di;
  float4 hd = *(const float4*)(hin + (size_t)d * 64 + lane * 4);
  float4 b4 = *(const float4*)(bias + lane * 4);
  float4 o;
  o.x = di * acc.x + di2 * hd.x + b4.x;
  o.y = di * acc.y + di2 * hd.y + b4.y;
  o.z = di * acc.z + di2 * hd.z + b4.z;
  o.w = di * acc.w + di2 * hd.w + b4.w;
  if (apply_lrelu) {
    o.x = (o.x > 0.f) ? o.x : LRELU_SLOPE * o.x;
    o.y = (o.y > 0.f) ? o.y : LRELU_SLOPE * o.y;
    o.z = (o.z > 0.f) ? o.z : LRELU_SLOPE * o.z;
    o.w = (o.w > 0.f) ? o.w : LRELU_SLOPE * o.w;
  }
  *(float4*)(hout + (size_t)d * 64 + lane * 4) = o;
}

// ---------------- BN column stats: per-block partials (atomic-free) ----------------
__launch_bounds__(256)
__global__ void k_stats(const float* __restrict__ h, float* __restrict__ partial, int N) {
  __shared__ float ls[256], lss[256];
  const int t = threadIdx.x;
  const int c = t & 63;
  float a = 0.f, a2 = 0.f;
  for (int n = blockIdx.x * 4 + (t >> 6); n < N; n += gridDim.x * 4) {
    float v = h[(size_t)n * 64 + c];
    a += v;
    a2 += v * v;
  }
  ls[t] = a;
  lss[t] = a2;
  __syncthreads();
  if (t < 64) {
    a = ls[t] + ls[t + 64] + ls[t + 128] + ls[t + 192];
    a2 = lss[t] + lss[t + 64] + lss[t + 128] + lss[t + 192];
    partial[blockIdx.x * 128 + t] = a;
    partial[blockIdx.x * 128 + 64 + t] = a2;
  }
}

__global__ void k_stats_reduce(const float* __restrict__ partial, float* __restrict__ s,
                               float* __restrict__ ss, int nb) {
  int t = threadIdx.x;  // 128 threads
  float a = 0.f;
  for (int b = 0; b < nb; ++b) a += partial[b * 128 + t];
  if (t < 64) s[t] = a;
  else ss[t - 64] = a;
}

// ---------------- BN apply + LeakyReLU ----------------
__launch_bounds__(256)
__global__ void k_bnapply(const float* __restrict__ hin, float* __restrict__ hout,
                          const float* __restrict__ s, const float* __restrict__ ss,
                          const float* __restrict__ g, const float* __restrict__ be,
                          int N) {
  int i = blockIdx.x * blockDim.x + threadIdx.x;  // index over N*16 float4s
  if (i >= N * 16) return;
  int c0 = (i & 15) * 4;
  float invN = 1.0f / (float)N;
  float4 v = ((const float4*)hin)[i];
  float o[4] = {v.x, v.y, v.z, v.w};
#pragma unroll
  for (int k = 0; k < 4; ++k) {
    int c = c0 + k;
    float mean = s[c] * invN;
    float var = ss[c] * invN - mean * mean;
    float scale = g[c] * rsqrtf(var + BN_EPS);
    float r = (o[k] - mean) * scale + be[c];
    o[k] = (r > 0.f) ? r : LRELU_SLOPE * r;
  }
  ((float4*)hout)[i] = make_float4(o[0], o[1], o[2], o[3]);
}

// ---------------- graph boundaries from sorted batch (atomic-free) ----------------
__global__ void k_gbounds(const int* __restrict__ batch, int* __restrict__ gstart,
                          int N, int G) {
  int i = blockIdx.x * blockDim.x + threadIdx.x;
  if (i >= N) return;
  int b = batch[i];
  int prev = (i == 0) ? -1 : batch[i - 1];
  for (int g = prev + 1; g <= b; ++g) gstart[g] = i;   // batch sorted => prev <= b
  if (i == N - 1) {
    for (int g = b + 1; g <= G; ++g) gstart[g] = N;
  }
}

// ---------------- pooling (max & mean per graph) + FC, fused ----------------
__launch_bounds__(256)
__global__ void k_pool(const float* __restrict__ h, const int* __restrict__ gstart,
                       const float* __restrict__ Wfc, const float* __restrict__ bfc,
                       float* __restrict__ out, int G) {
  __shared__ float lmx[256], lsm[256], red[128];
  const int g = blockIdx.x;
  const int t = threadIdx.x;
  const int c = t & 63;
  const int sub = t >> 6;
  const int n0 = gstart[g];
  const int n1 = gstart[g + 1];
  float mx = -INFINITY, sm = 0.f;
  for (int n = n0 + sub; n < n1; n += 4) {
    float v = h[(size_t)n * 64 + c];
    mx = fmaxf(mx, v);
    sm += v;
  }
  lmx[t] = mx;
  lsm[t] = sm;
  __syncthreads();
  if (t < 64) {
    mx = fmaxf(fmaxf(lmx[t], lmx[t + 64]), fmaxf(lmx[t + 128], lmx[t + 192]));
    sm = lsm[t] + lsm[t + 64] + lsm[t + 128] + lsm[t + 192];
    float cntf = (float)(n1 - n0);
    float mean = sm / fmaxf(cntf, 1.0f);
    red[t] = mx * Wfc[t];
    red[t + 64] = mean * Wfc[64 + t];
  }
  __syncthreads();
  for (int st = 64; st >= 1; st >>= 1) {
    if (t < st) red[t] += red[t + st];
    __syncthreads();
  }
  if (t == 0) out[g] = red[0] + bfc[0];
}

// ---------------- host launch ----------------
extern "C" void kernel_launch(void* const* d_in, const int* in_sizes, int n_in,
                              void* d_out, int out_size, void* d_ws, size_t ws_size,
                              hipStream_t stream) {
  const float* x = (const float*)d_in[0];
  const int* ei = (const int*)d_in[1];
  const int* batch = (const int*)d_in[2];
  const float* eattr = (const float*)d_in[3];
  const float* W0 = (const float*)d_in[4];
  const float* b0 = (const float*)d_in[5];
  const float* g0 = (const float*)d_in[6];
  const float* be0 = (const float*)d_in[7];
  const float* W1 = (const float*)d_in[8];
  const float* b1 = (const float*)d_in[9];
  const float* g1 = (const float*)d_in[10];
  const float* be1 = (const float*)d_in[11];
  const float* W2 = (const float*)d_in[12];
  const float* b2 = (const float*)d_in[13];
  const float* W3 = (const float*)d_in[14];
  const float* b3 = (const float*)d_in[15];
  const float* Wfc = (const float*)d_in[16];
  const float* bfc = (const float*)d_in[17];
  float* out = (float*)d_out;

  const int N = in_sizes[2];       // batch is [N]
  const int E = in_sizes[3];       // edge_attr is [E]
  const int CIN = in_sizes[0] / N; // 128
  const int G = out_size;          // [G,1]

  // workspace carve-up (256B-aligned slices)
  size_t off = 0;
  auto alloc = [&](size_t bytes) -> void* {
    void* p = (char*)d_ws + off;
    off += (bytes + 255) & ~(size_t)255;
    return p;
  };
  unsigned long long* packed = (unsigned long long*)alloc((size_t)N * 8);
  float* dinv = (float*)alloc((size_t)N * 4);
  int* rowstart = (int*)alloc((size_t)(N + 1) * 4);
  int* rank = (int*)alloc((size_t)E * 4);
  int* bsum = (int*)alloc(1024 * 4);
  unsigned long long* colval = (unsigned long long*)alloc((size_t)E * 8);
  float* A = (float*)alloc((size_t)N * 64 * 4);
  float* B = (float*)alloc((size_t)N * 64 * 4);
  float* sums = (float*)alloc(256 * 4);   // s0|ss0|s1|ss1
  float* partial = (float*)alloc(256 * 128 * 4);
  int* gstart = (int*)alloc((size_t)(G + 1) * 4);
  (void)ws_size; (void)n_in; (void)CIN;

  const int nb = ceil_div(N, 1024);

  // graph structure (layer-invariant)
  k_init<<<ceil_div(N, 256), 256, 0, stream>>>(packed, N);
  k_edge_count<<<ceil_div(E, 1024), 256, 0, stream>>>(ei, eattr, packed, rank, E);
  k_scan1<<<nb, 256, 0, stream>>>(packed, rowstart, bsum, N);
  k_scan2<<<1, 256, 0, stream>>>(bsum, nb);
  k_scan3<<<ceil_div(N + 1, 256), 256, 0, stream>>>(rowstart, bsum, packed, dinv, N, E);
  k_fill<<<ceil_div(E, 256), 256, 0, stream>>>(ei, eattr, rowstart, rank, dinv, colval, E);
  k_gbounds<<<ceil_div(N, 256), 256, 0, stream>>>(batch, gstart, N, G);

  // layer 0: gemm(x,W0)->A; agg A->B; stats(B); bn+lrelu B->A
  k_gemm<128><<<ceil_div(N, 64), 256, 0, stream>>>(x, W0, A, N);
  k_agg<<<ceil_div(N, 16), 256, 0, stream>>>(A, B, b0, dinv, rowstart, colval, N, 0);
  k_stats<<<256, 256, 0, stream>>>(B, partial, N);
  k_stats_reduce<<<1, 128, 0, stream>>>(partial, sums + 0, sums + 64, 256);
  k_bnapply<<<ceil_div(N * 16, 256), 256, 0, stream>>>(B, A, sums + 0, sums + 64, g0, be0, N);

  // layer 1: gemm(A,W1)->B; agg B->A; stats(A); bn+lrelu A->B
  k_gemm<64><<<ceil_div(N, 64), 256, 0, stream>>>(A, W1, B, N);
  k_agg<<<ceil_div(N, 16), 256, 0, stream>>>(B, A, b1, dinv, rowstart, colval, N, 0);
  k_stats<<<256, 256, 0, stream>>>(A, partial, N);
  k_stats_reduce<<<1, 128, 0, stream>>>(partial, sums + 128, sums + 192, 256);
  k_bnapply<<<ceil_div(N * 16, 256), 256, 0, stream>>>(A, B, sums + 128, sums + 192, g1, be1, N);

  // layer 2: gemm(B,W2)->A; agg(+lrelu) A->B
  k_gemm<64><<<ceil_div(N, 64), 256, 0, stream>>>(B, W2, A, N);
  k_agg<<<ceil_div(N, 16), 256, 0, stream>>>(A, B, b2, dinv, rowstart, colval, N, 1);

  // layer 3: gemm(B,W3)->A; agg(+lrelu) A->B
  k_gemm<64><<<ceil_div(N, 64), 256, 0, stream>>>(B, W3, A, N);
  k_agg<<<ceil_div(N, 16), 256, 0, stream>>>(A, B, b3, dinv, rowstart, colval, N, 1);

  // pooling + FC
  k_pool<<<G, 256, 0, stream>>>(B, gstart, Wfc, bfc, out, G);
}

// Round 7
// 779.272 us; speedup vs baseline: 1.2756x; 1.0502x over previous
//
#include <hip/hip_runtime.h>
#include <math.h>

#define LRELU_SLOPE 0.01f
#define BN_EPS 1e-5f
#define WQ_SCALE 1048576.0f        /* 2^20 fixed-point for per-dst weighted degree */
#define WQ_INV   9.5367431640625e-7f

static inline int ceil_div(int a, int b) { return (a + b - 1) / b; }

// ============ Phase B1: per-(bucket,block) histogram, bucket = dst>>7 ============
// 256 blocks, each owns a contiguous edge chunk. LDS atomics only.
__launch_bounds__(256)
__global__ void b1_hist(const int* __restrict__ ei, int* __restrict__ histT,
                        int E, int chunk, int nbuck) {
  __shared__ unsigned int hist[1024];
  const int t = threadIdx.x;
  const int blk = blockIdx.x;
#pragma unroll
  for (int l = 0; l < 4; ++l) hist[t + l * 256] = 0;
  __syncthreads();
  const int e0 = blk * chunk;
  const int e1 = min(e0 + chunk, E);
  for (int e = e0 + t; e < e1; e += 256) {
    int d = ei[E + e];
    atomicAdd(&hist[d >> 7], 1u);
  }
  __syncthreads();
#pragma unroll
  for (int l = 0; l < 4; ++l) {
    int b = t + l * 256;
    if (b < nbuck) histT[(size_t)b * 256 + blk] = (int)hist[b];
  }
}

// ============ int exclusive scan (2-level), M up to 256*1024 ============
__global__ void scan1i(const int* __restrict__ in, int* __restrict__ out,
                       int* __restrict__ bsum, int n) {
  __shared__ int lds[256];
  const int t = threadIdx.x;
  const int base = blockIdx.x * 1024 + t * 4;
  int v0 = 0, v1 = 0, v2 = 0, v3 = 0;
  if (base + 0 < n) v0 = in[base + 0];
  if (base + 1 < n) v1 = in[base + 1];
  if (base + 2 < n) v2 = in[base + 2];
  if (base + 3 < n) v3 = in[base + 3];
  int s = v0 + v1 + v2 + v3;
  lds[t] = s;
  __syncthreads();
#pragma unroll
  for (int off = 1; off < 256; off <<= 1) {
    int y = 0;
    if (t >= off) y = lds[t - off];
    __syncthreads();
    if (t >= off) lds[t] += y;
    __syncthreads();
  }
  int incl = lds[t];
  int excl = incl - s;
  if (base + 0 < n) out[base + 0] = excl;
  if (base + 1 < n) out[base + 1] = excl + v0;
  if (base + 2 < n) out[base + 2] = excl + v0 + v1;
  if (base + 3 < n) out[base + 3] = excl + v0 + v1 + v2;
  if (t == 255) bsum[blockIdx.x] = incl;
}

__global__ void scan2i(int* __restrict__ bsum, int nb) {  // in-place exclusive, nb<=256
  __shared__ int lds[256];
  int t = threadIdx.x;
  int v = (t < nb) ? bsum[t] : 0;
  lds[t] = v;
  __syncthreads();
#pragma unroll
  for (int off = 1; off < 256; off <<= 1) {
    int y = 0;
    if (t >= off) y = lds[t - off];
    __syncthreads();
    if (t >= off) lds[t] += y;
    __syncthreads();
  }
  if (t < nb) bsum[t] = lds[t] - v;
}

__global__ void scan3i(int* __restrict__ data, const int* __restrict__ bscan, int n) {
  int i = blockIdx.x * blockDim.x + threadIdx.x;
  if (i < n) data[i] += bscan[i >> 10];
}

// ============ Phase B3: scatter edges into bucket-grouped array ============
// bucketed[p] = (dst&127)<<57 | src<<32 | bits(w). LDS cursors seeded with scanned bases.
__launch_bounds__(256)
__global__ void b3_scatter(const int* __restrict__ ei, const float* __restrict__ w,
                           const int* __restrict__ histS,
                           unsigned long long* __restrict__ bucketed,
                           int E, int chunk, int nbuck) {
  __shared__ unsigned int cursor[1024];
  const int t = threadIdx.x;
  const int blk = blockIdx.x;
#pragma unroll
  for (int l = 0; l < 4; ++l) {
    int b = t + l * 256;
    cursor[b] = (b < nbuck) ? (unsigned int)histS[(size_t)b * 256 + blk] : 0u;
  }
  __syncthreads();
  const int e0 = blk * chunk;
  const int e1 = min(e0 + chunk, E);
  for (int e = e0 + t; e < e1; e += 256) {
    int s = ei[e];
    int d = ei[E + e];
    unsigned int pos = atomicAdd(&cursor[d >> 7], 1u);
    unsigned long long p = ((unsigned long long)(unsigned int)(d & 127) << 57) |
                           ((unsigned long long)(unsigned int)s << 32) |
                           (unsigned long long)__float_as_uint(w[e]);
    bucketed[pos] = p;
  }
}

// ============ Phase C1: per-bucket degree + rowstart (LDS only) ============
__launch_bounds__(256)
__global__ void c1_degree(const unsigned long long* __restrict__ bucketed,
                          const int* __restrict__ histS,
                          int* __restrict__ rowstart, float* __restrict__ dinv,
                          int N, int E, int nbuck) {
  __shared__ unsigned int cnt[128], wsum[128];
  __shared__ int sc[128];
  const int t = threadIdx.x;
  const int b = blockIdx.x;
  if (t < 128) { cnt[t] = 0; wsum[t] = 0; }
  __syncthreads();
  const int r0 = histS[(size_t)b * 256];
  const int r1 = (b + 1 < nbuck) ? histS[(size_t)(b + 1) * 256] : E;
  for (int r = r0 + t; r < r1; r += 256) {
    unsigned long long p = bucketed[r];
    int d7 = (int)(p >> 57);
    float wv = __uint_as_float((unsigned int)p);
    atomicAdd(&cnt[d7], 1u);
    atomicAdd(&wsum[d7], (unsigned int)__float2uint_rn(wv * WQ_SCALE));
  }
  __syncthreads();
  if (t < 128) sc[t] = (int)cnt[t];
  __syncthreads();
#pragma unroll
  for (int off = 1; off < 128; off <<= 1) {
    int y = 0;
    if (t < 128 && t >= off) y = sc[t - off];
    __syncthreads();
    if (t < 128 && t >= off) sc[t] += y;
    __syncthreads();
  }
  if (t < 128) {
    int node = (b << 7) + t;
    if (node < N) {
      rowstart[node] = r0 + sc[t] - (int)cnt[t];   // exclusive
      float deg = 1.0f + (float)wsum[t] * WQ_INV;  // self-loop + edge weights
      dinv[node] = rsqrtf(deg);
    }
  }
  if (b == 0 && t == 0) rowstart[N] = E;
}

// ============ Phase C2: per-bucket CSR fill, colval[p]=(src<<32)|bits(w*dinv[src]) ============
__launch_bounds__(256)
__global__ void c2_fill(const unsigned long long* __restrict__ bucketed,
                        const int* __restrict__ histS,
                        const int* __restrict__ rowstart, const float* __restrict__ dinv,
                        unsigned long long* __restrict__ colval,
                        int N, int E, int nbuck) {
  __shared__ unsigned int cursor[128];
  const int t = threadIdx.x;
  const int b = blockIdx.x;
  if (t < 128) {
    int node = (b << 7) + t;
    cursor[t] = (node < N) ? (unsigned int)rowstart[node] : 0u;
  }
  __syncthreads();
  const int r0 = histS[(size_t)b * 256];
  const int r1 = (b + 1 < nbuck) ? histS[(size_t)(b + 1) * 256] : E;
  for (int r = r0 + t; r < r1; r += 256) {
    unsigned long long p = bucketed[r];
    int d7 = (int)(p >> 57);
    int s = (int)((p >> 32) & 0x1FFFFFF);
    float wv = __uint_as_float((unsigned int)p);
    unsigned int pos = atomicAdd(&cursor[d7], 1u);
    float v = wv * dinv[s];
    colval[pos] = ((unsigned long long)(unsigned int)s << 32) |
                  (unsigned long long)__float_as_uint(v);
  }
}

// ---------------- GEMM: H[N,64] = X[N,K] @ W[K,64]  (fp32, VALU) ----------------
// Register-blocked 16x16 threads, 64x64 tile, 4x4 acc/thread (see r5 post-mortem:
// a 64-float acc array never stays in arch VGPRs; 4x4 does).
template <int K>
__launch_bounds__(256, 4)
__global__ void k_gemm(const float* __restrict__ X, const float* __restrict__ W,
                       float* __restrict__ H, int N) {
  __shared__ float Xl[64 * 68];
  __shared__ float Wl[64 * 64];
  const int t = threadIdx.x;
  const int tx = t & 15;
  const int ty = t >> 4;
  const int n0 = blockIdx.x * 64;

  float4 acc[4];
#pragma unroll
  for (int r = 0; r < 4; ++r) acc[r] = make_float4(0.f, 0.f, 0.f, 0.f);

  for (int kt = 0; kt < K; kt += 64) {
    __syncthreads();
#pragma unroll
    for (int l = 0; l < 4; ++l) {
      int idx = t + l * 256;
      int node = idx >> 4;
      int kq = idx & 15;
      int gn = n0 + node;
      float4 v = make_float4(0.f, 0.f, 0.f, 0.f);
      if (gn < N) v = *(const float4*)(X + (size_t)gn * K + kt + 4 * kq);
      int kb = 4 * kq;
      Xl[(kb + 0) * 68 + node] = v.x;
      Xl[(kb + 1) * 68 + node] = v.y;
      Xl[(kb + 2) * 68 + node] = v.z;
      Xl[(kb + 3) * 68 + node] = v.w;
    }
#pragma unroll
    for (int l = 0; l < 4; ++l) {
      int idx = t + l * 256;
      ((float4*)Wl)[idx] = *(const float4*)(W + (size_t)(kt + (idx >> 4)) * 64 + 4 * (idx & 15));
    }
    __syncthreads();
#pragma unroll 8
    for (int k = 0; k < 64; ++k) {
      float4 xv = *(const float4*)(Xl + k * 68 + 4 * ty);
      float4 wv = *(const float4*)(Wl + k * 64 + 4 * tx);
      acc[0].x += xv.x * wv.x; acc[0].y += xv.x * wv.y; acc[0].z += xv.x * wv.z; acc[0].w += xv.x * wv.w;
      acc[1].x += xv.y * wv.x; acc[1].y += xv.y * wv.y; acc[1].z += xv.y * wv.z; acc[1].w += xv.y * wv.w;
      acc[2].x += xv.z * wv.x; acc[2].y += xv.z * wv.y; acc[2].z += xv.z * wv.z; acc[2].w += xv.z * wv.w;
      acc[3].x += xv.w * wv.x; acc[3].y += xv.w * wv.y; acc[3].z += xv.w * wv.z; acc[3].w += xv.w * wv.w;
    }
  }
#pragma unroll
  for (int r = 0; r < 4; ++r) {
    int gn = n0 + 4 * ty + r;
    if (gn < N) *(float4*)(H + (size_t)gn * 64 + 4 * tx) = acc[r];
  }
}

// ---------------- CSR aggregation: out[d] = dinv[d]*sum(val*h[src]) + dinv[d]^2*h[d] + b ----
__launch_bounds__(256)
__global__ void k_agg(const float* __restrict__ hin, float* __restrict__ hout,
                      const float* __restrict__ bias, const float* __restrict__ dinv,
                      const int* __restrict__ rowstart,
                      const unsigned long long* __restrict__ colval,
                      int N, int apply_lrelu) {
  const int t = threadIdx.x;
  const int grp = t >> 4;
  const int lane = t & 15;
  const int d = blockIdx.x * 16 + grp;
  if (d >= N) return;
  const int r0 = rowstart[d];
  const int r1 = rowstart[d + 1];
  float4 acc = make_float4(0.f, 0.f, 0.f, 0.f);
  for (int r = r0; r < r1; ++r) {
    unsigned long long cv = colval[r];
    int s = (int)(cv >> 32);
    float v = __uint_as_float((unsigned int)cv);
    float4 hv = *(const float4*)(hin + (size_t)s * 64 + lane * 4);
    acc.x += v * hv.x;
    acc.y += v * hv.y;
    acc.z += v * hv.z;
    acc.w += v * hv.w;
  }
  float di = dinv[d];
  float di2 = di * di;
  float4 hd = *(const float4*)(hin + (size_t)d * 64 + lane * 4);
  float4 b4 = *(const float4*)(bias + lane * 4);
  float4 o;
  o.x = di * acc.x + di2 * hd.x + b4.x;
  o.y = di * acc.y + di2 * hd.y + b4.y;
  o.z = di * acc.z + di2 * hd.z + b4.z;
  o.w = di * acc.w + di2 * hd.w + b4.w;
  if (apply_lrelu) {
    o.x = (o.x > 0.f) ? o.x : LRELU_SLOPE * o.x;
    o.y = (o.y > 0.f) ? o.y : LRELU_SLOPE * o.y;
    o.z = (o.z > 0.f) ? o.z : LRELU_SLOPE * o.z;
    o.w = (o.w > 0.f) ? o.w : LRELU_SLOPE * o.w;
  }
  *(float4*)(hout + (size_t)d * 64 + lane * 4) = o;
}

// ---------------- BN column stats: per-block partials (atomic-free) ----------------
__launch_bounds__(256)
__global__ void k_stats(const float* __restrict__ h, float* __restrict__ partial, int N) {
  __shared__ float ls[256], lss[256];
  const int t = threadIdx.x;
  const int c = t & 63;
  float a = 0.f, a2 = 0.f;
  for (int n = blockIdx.x * 4 + (t >> 6); n < N; n += gridDim.x * 4) {
    float v = h[(size_t)n * 64 + c];
    a += v;
    a2 += v * v;
  }
  ls[t] = a;
  lss[t] = a2;
  __syncthreads();
  if (t < 64) {
    a = ls[t] + ls[t + 64] + ls[t + 128] + ls[t + 192];
    a2 = lss[t] + lss[t + 64] + lss[t + 128] + lss[t + 192];
    partial[blockIdx.x * 128 + t] = a;
    partial[blockIdx.x * 128 + 64 + t] = a2;
  }
}

__global__ void k_stats_reduce(const float* __restrict__ partial, float* __restrict__ s,
                               float* __restrict__ ss, int nb) {
  int t = threadIdx.x;  // 128 threads
  float a = 0.f;
  for (int b = 0; b < nb; ++b) a += partial[b * 128 + t];
  if (t < 64) s[t] = a;
  else ss[t - 64] = a;
}

// ---------------- BN apply + LeakyReLU ----------------
__launch_bounds__(256)
__global__ void k_bnapply(const float* __restrict__ hin, float* __restrict__ hout,
                          const float* __restrict__ s, const float* __restrict__ ss,
                          const float* __restrict__ g, const float* __restrict__ be,
                          int N) {
  int i = blockIdx.x * blockDim.x + threadIdx.x;  // index over N*16 float4s
  if (i >= N * 16) return;
  int c0 = (i & 15) * 4;
  float invN = 1.0f / (float)N;
  float4 v = ((const float4*)hin)[i];
  float o[4] = {v.x, v.y, v.z, v.w};
#pragma unroll
  for (int k = 0; k < 4; ++k) {
    int c = c0 + k;
    float mean = s[c] * invN;
    float var = ss[c] * invN - mean * mean;
    float scale = g[c] * rsqrtf(var + BN_EPS);
    float r = (o[k] - mean) * scale + be[c];
    o[k] = (r > 0.f) ? r : LRELU_SLOPE * r;
  }
  ((float4*)hout)[i] = make_float4(o[0], o[1], o[2], o[3]);
}

// ---------------- graph boundaries from sorted batch (atomic-free) ----------------
__global__ void k_gbounds(const int* __restrict__ batch, int* __restrict__ gstart,
                          int N, int G) {
  int i = blockIdx.x * blockDim.x + threadIdx.x;
  if (i >= N) return;
  int b = batch[i];
  int prev = (i == 0) ? -1 : batch[i - 1];
  for (int g = prev + 1; g <= b; ++g) gstart[g] = i;   // batch sorted => prev <= b
  if (i == N - 1) {
    for (int g = b + 1; g <= G; ++g) gstart[g] = N;
  }
}

// ---------------- pooling (max & mean per graph) + FC, fused ----------------
__launch_bounds__(256)
__global__ void k_pool(const float* __restrict__ h, const int* __restrict__ gstart,
                       const float* __restrict__ Wfc, const float* __restrict__ bfc,
                       float* __restrict__ out, int G) {
  __shared__ float lmx[256], lsm[256], red[128];
  const int g = blockIdx.x;
  const int t = threadIdx.x;
  const int c = t & 63;
  const int sub = t >> 6;
  const int n0 = gstart[g];
  const int n1 = gstart[g + 1];
  float mx = -INFINITY, sm = 0.f;
  for (int n = n0 + sub; n < n1; n += 4) {
    float v = h[(size_t)n * 64 + c];
    mx = fmaxf(mx, v);
    sm += v;
  }
  lmx[t] = mx;
  lsm[t] = sm;
  __syncthreads();
  if (t < 64) {
    mx = fmaxf(fmaxf(lmx[t], lmx[t + 64]), fmaxf(lmx[t + 128], lmx[t + 192]));
    sm = lsm[t] + lsm[t + 64] + lsm[t + 128] + lsm[t + 192];
    float cntf = (float)(n1 - n0);
    float mean = sm / fmaxf(cntf, 1.0f);
    red[t] = mx * Wfc[t];
    red[t + 64] = mean * Wfc[64 + t];
  }
  __syncthreads();
  for (int st = 64; st >= 1; st >>= 1) {
    if (t < st) red[t] += red[t + st];
    __syncthreads();
  }
  if (t == 0) out[g] = red[0] + bfc[0];
}

// ---------------- host launch ----------------
extern "C" void kernel_launch(void* const* d_in, const int* in_sizes, int n_in,
                              void* d_out, int out_size, void* d_ws, size_t ws_size,
                              hipStream_t stream) {
  const float* x = (const float*)d_in[0];
  const int* ei = (const int*)d_in[1];
  const int* batch = (const int*)d_in[2];
  const float* eattr = (const float*)d_in[3];
  const float* W0 = (const float*)d_in[4];
  const float* b0 = (const float*)d_in[5];
  const float* g0 = (const float*)d_in[6];
  const float* be0 = (const float*)d_in[7];
  const float* W1 = (const float*)d_in[8];
  const float* b1 = (const float*)d_in[9];
  const float* g1 = (const float*)d_in[10];
  const float* be1 = (const float*)d_in[11];
  const float* W2 = (const float*)d_in[12];
  const float* b2 = (const float*)d_in[13];
  const float* W3 = (const float*)d_in[14];
  const float* b3 = (const float*)d_in[15];
  const float* Wfc = (const float*)d_in[16];
  const float* bfc = (const float*)d_in[17];
  float* out = (float*)d_out;

  const int N = in_sizes[2];       // batch is [N]
  const int E = in_sizes[3];       // edge_attr is [E]
  const int CIN = in_sizes[0] / N; // 128
  const int G = out_size;          // [G,1]
  const int nbuck = ceil_div(N, 128);
  const int chunk = ceil_div(E, 256);
  const int M = nbuck * 256;       // hist matrix elements

  // workspace carve-up (256B-aligned slices)
  size_t off = 0;
  auto alloc = [&](size_t bytes) -> void* {
    void* p = (char*)d_ws + off;
    off += (bytes + 255) & ~(size_t)255;
    return p;
  };
  int* histT = (int*)alloc((size_t)1024 * 256 * 4);   // raw counts [bucket][block]
  int* histS = (int*)alloc((size_t)1024 * 256 * 4);   // scanned
  int* bsum = (int*)alloc(1024 * 4);
  unsigned long long* bucketed = (unsigned long long*)alloc((size_t)E * 8);
  float* dinv = (float*)alloc((size_t)N * 4);
  int* rowstart = (int*)alloc((size_t)(N + 1) * 4);
  unsigned long long* colval = (unsigned long long*)alloc((size_t)E * 8);
  float* A = (float*)alloc((size_t)N * 64 * 4);
  float* B = (float*)alloc((size_t)N * 64 * 4);
  float* sums = (float*)alloc(256 * 4);   // s0|ss0|s1|ss1
  float* partial = (float*)alloc(256 * 128 * 4);
  int* gstart = (int*)alloc((size_t)(G + 1) * 4);
  (void)ws_size; (void)n_in; (void)CIN;

  // ---- graph structure (layer-invariant, zero device-scope atomics) ----
  b1_hist<<<256, 256, 0, stream>>>(ei, histT, E, chunk, nbuck);
  const int nbs = ceil_div(M, 1024);
  scan1i<<<nbs, 256, 0, stream>>>(histT, histS, bsum, M);
  scan2i<<<1, 256, 0, stream>>>(bsum, nbs);
  scan3i<<<ceil_div(M, 256), 256, 0, stream>>>(histS, bsum, M);
  b3_scatter<<<256, 256, 0, stream>>>(ei, eattr, histS, bucketed, E, chunk, nbuck);
  c1_degree<<<nbuck, 256, 0, stream>>>(bucketed, histS, rowstart, dinv, N, E, nbuck);
  c2_fill<<<nbuck, 256, 0, stream>>>(bucketed, histS, rowstart, dinv, colval, N, E, nbuck);
  k_gbounds<<<ceil_div(N, 256), 256, 0, stream>>>(batch, gstart, N, G);

  // layer 0: gemm(x,W0)->A; agg A->B; stats(B); bn+lrelu B->A
  k_gemm<128><<<ceil_div(N, 64), 256, 0, stream>>>(x, W0, A, N);
  k_agg<<<ceil_div(N, 16), 256, 0, stream>>>(A, B, b0, dinv, rowstart, colval, N, 0);
  k_stats<<<256, 256, 0, stream>>>(B, partial, N);
  k_stats_reduce<<<1, 128, 0, stream>>>(partial, sums + 0, sums + 64, 256);
  k_bnapply<<<ceil_div(N * 16, 256), 256, 0, stream>>>(B, A, sums + 0, sums + 64, g0, be0, N);

  // layer 1: gemm(A,W1)->B; agg B->A; stats(A); bn+lrelu A->B
  k_gemm<64><<<ceil_div(N, 64), 256, 0, stream>>>(A, W1, B, N);
  k_agg<<<ceil_div(N, 16), 256, 0, stream>>>(B, A, b1, dinv, rowstart, colval, N, 0);
  k_stats<<<256, 256, 0, stream>>>(A, partial, N);
  k_stats_reduce<<<1, 128, 0, stream>>>(partial, sums + 128, sums + 192, 256);
  k_bnapply<<<ceil_div(N * 16, 256), 256, 0, stream>>>(A, B, sums + 128, sums + 192, g1, be1, N);

  // layer 2: gemm(B,W2)->A; agg(+lrelu) A->B
  k_gemm<64><<<ceil_div(N, 64), 256, 0, stream>>>(B, W2, A, N);
  k_agg<<<ceil_div(N, 16), 256, 0, stream>>>(A, B, b2, dinv, rowstart, colval, N, 1);

  // layer 3: gemm(B,W3)->A; agg(+lrelu) A->B
  k_gemm<64><<<ceil_div(N, 64), 256, 0, stream>>>(B, W3, A, N);
  k_agg<<<ceil_div(N, 16), 256, 0, stream>>>(A, B, b3, dinv, rowstart, colval, N, 1);

  // pooling + FC
  k_pool<<<G, 256, 0, stream>>>(B, gstart, Wfc, bfc, out, G);
}

// Round 8
// 738.278 us; speedup vs baseline: 1.3464x; 1.0555x over previous
//
#include <hip/hip_runtime.h>
#include <math.h>

#define LRELU_SLOPE 0.01f
#define BN_EPS 1e-5f
#define WQ_SCALE 1048576.0f        /* 2^20 fixed-point for per-dst weighted degree */
#define WQ_INV   9.5367431640625e-7f

static inline int ceil_div(int a, int b) { return (a + b - 1) / b; }

// ============ Phase B1: per-(bucket,block) histogram, bucket = dst>>7 ============
__launch_bounds__(256)
__global__ void b1_hist(const int* __restrict__ ei, int* __restrict__ histT,
                        int E, int chunk, int nbuck) {
  __shared__ unsigned int hist[1024];
  const int t = threadIdx.x;
  const int blk = blockIdx.x;
#pragma unroll
  for (int l = 0; l < 4; ++l) hist[t + l * 256] = 0;
  __syncthreads();
  const int e0 = blk * chunk;
  const int e1 = min(e0 + chunk, E);
  for (int e = e0 + t; e < e1; e += 256) {
    int d = ei[E + e];
    atomicAdd(&hist[d >> 7], 1u);
  }
  __syncthreads();
#pragma unroll
  for (int l = 0; l < 4; ++l) {
    int b = t + l * 256;
    if (b < nbuck) histT[(size_t)b * 256 + blk] = (int)hist[b];
  }
}

// ============ int exclusive scan (2-level), M up to 256*1024 ============
__global__ void scan1i(const int* __restrict__ in, int* __restrict__ out,
                       int* __restrict__ bsum, int n) {
  __shared__ int lds[256];
  const int t = threadIdx.x;
  const int base = blockIdx.x * 1024 + t * 4;
  int v0 = 0, v1 = 0, v2 = 0, v3 = 0;
  if (base + 0 < n) v0 = in[base + 0];
  if (base + 1 < n) v1 = in[base + 1];
  if (base + 2 < n) v2 = in[base + 2];
  if (base + 3 < n) v3 = in[base + 3];
  int s = v0 + v1 + v2 + v3;
  lds[t] = s;
  __syncthreads();
#pragma unroll
  for (int off = 1; off < 256; off <<= 1) {
    int y = 0;
    if (t >= off) y = lds[t - off];
    __syncthreads();
    if (t >= off) lds[t] += y;
    __syncthreads();
  }
  int incl = lds[t];
  int excl = incl - s;
  if (base + 0 < n) out[base + 0] = excl;
  if (base + 1 < n) out[base + 1] = excl + v0;
  if (base + 2 < n) out[base + 2] = excl + v0 + v1;
  if (base + 3 < n) out[base + 3] = excl + v0 + v1 + v2;
  if (t == 255) bsum[blockIdx.x] = incl;
}

__global__ void scan2i(int* __restrict__ bsum, int nb) {  // in-place exclusive, nb<=256
  __shared__ int lds[256];
  int t = threadIdx.x;
  int v = (t < nb) ? bsum[t] : 0;
  lds[t] = v;
  __syncthreads();
#pragma unroll
  for (int off = 1; off < 256; off <<= 1) {
    int y = 0;
    if (t >= off) y = lds[t - off];
    __syncthreads();
    if (t >= off) lds[t] += y;
    __syncthreads();
  }
  if (t < nb) bsum[t] = lds[t] - v;
}

__global__ void scan3i(int* __restrict__ data, const int* __restrict__ bscan, int n) {
  int i = blockIdx.x * blockDim.x + threadIdx.x;
  if (i < n) data[i] += bscan[i >> 10];
}

// ============ Phase B3: scatter edges into bucket-grouped array ============
__launch_bounds__(256)
__global__ void b3_scatter(const int* __restrict__ ei, const float* __restrict__ w,
                           const int* __restrict__ histS,
                           unsigned long long* __restrict__ bucketed,
                           int E, int chunk, int nbuck) {
  __shared__ unsigned int cursor[1024];
  const int t = threadIdx.x;
  const int blk = blockIdx.x;
#pragma unroll
  for (int l = 0; l < 4; ++l) {
    int b = t + l * 256;
    cursor[b] = (b < nbuck) ? (unsigned int)histS[(size_t)b * 256 + blk] : 0u;
  }
  __syncthreads();
  const int e0 = blk * chunk;
  const int e1 = min(e0 + chunk, E);
  for (int e = e0 + t; e < e1; e += 256) {
    int s = ei[e];
    int d = ei[E + e];
    unsigned int pos = atomicAdd(&cursor[d >> 7], 1u);
    unsigned long long p = ((unsigned long long)(unsigned int)(d & 127) << 57) |
                           ((unsigned long long)(unsigned int)s << 32) |
                           (unsigned long long)__float_as_uint(w[e]);
    bucketed[pos] = p;
  }
}

// ============ Phase C1: per-bucket degree + rowstart (LDS only) ============
__launch_bounds__(256)
__global__ void c1_degree(const unsigned long long* __restrict__ bucketed,
                          const int* __restrict__ histS,
                          int* __restrict__ rowstart, float* __restrict__ dinv,
                          int N, int E, int nbuck) {
  __shared__ unsigned int cnt[128], wsum[128];
  __shared__ int sc[128];
  const int t = threadIdx.x;
  const int b = blockIdx.x;
  if (t < 128) { cnt[t] = 0; wsum[t] = 0; }
  __syncthreads();
  const int r0 = histS[(size_t)b * 256];
  const int r1 = (b + 1 < nbuck) ? histS[(size_t)(b + 1) * 256] : E;
  for (int r = r0 + t; r < r1; r += 256) {
    unsigned long long p = bucketed[r];
    int d7 = (int)(p >> 57);
    float wv = __uint_as_float((unsigned int)p);
    atomicAdd(&cnt[d7], 1u);
    atomicAdd(&wsum[d7], (unsigned int)__float2uint_rn(wv * WQ_SCALE));
  }
  __syncthreads();
  if (t < 128) sc[t] = (int)cnt[t];
  __syncthreads();
#pragma unroll
  for (int off = 1; off < 128; off <<= 1) {
    int y = 0;
    if (t < 128 && t >= off) y = sc[t - off];
    __syncthreads();
    if (t < 128 && t >= off) sc[t] += y;
    __syncthreads();
  }
  if (t < 128) {
    int node = (b << 7) + t;
    if (node < N) {
      rowstart[node] = r0 + sc[t] - (int)cnt[t];   // exclusive
      float deg = 1.0f + (float)wsum[t] * WQ_INV;  // self-loop + edge weights
      dinv[node] = rsqrtf(deg);
    }
  }
  if (b == 0 && t == 0) rowstart[N] = E;
}

// ============ Phase C2: per-bucket CSR fill ============
__launch_bounds__(256)
__global__ void c2_fill(const unsigned long long* __restrict__ bucketed,
                        const int* __restrict__ histS,
                        const int* __restrict__ rowstart, const float* __restrict__ dinv,
                        unsigned long long* __restrict__ colval,
                        int N, int E, int nbuck) {
  __shared__ unsigned int cursor[128];
  const int t = threadIdx.x;
  const int b = blockIdx.x;
  if (t < 128) {
    int node = (b << 7) + t;
    cursor[t] = (node < N) ? (unsigned int)rowstart[node] : 0u;
  }
  __syncthreads();
  const int r0 = histS[(size_t)b * 256];
  const int r1 = (b + 1 < nbuck) ? histS[(size_t)(b + 1) * 256] : E;
  for (int r = r0 + t; r < r1; r += 256) {
    unsigned long long p = bucketed[r];
    int d7 = (int)(p >> 57);
    int s = (int)((p >> 32) & 0x1FFFFFF);
    float wv = __uint_as_float((unsigned int)p);
    unsigned int pos = atomicAdd(&cursor[d7], 1u);
    float v = wv * dinv[s];
    colval[pos] = ((unsigned long long)(unsigned int)s << 32) |
                  (unsigned long long)__float_as_uint(v);
  }
}

// ---------------- GEMM: H[N,64] = X[N,K] @ W[K,64]  (fp32, VALU) ----------------
template <int K>
__launch_bounds__(256, 4)
__global__ void k_gemm(const float* __restrict__ X, const float* __restrict__ W,
                       float* __restrict__ H, int N) {
  __shared__ float Xl[64 * 68];
  __shared__ float Wl[64 * 64];
  const int t = threadIdx.x;
  const int tx = t & 15;
  const int ty = t >> 4;
  const int n0 = blockIdx.x * 64;

  float4 acc[4];
#pragma unroll
  for (int r = 0; r < 4; ++r) acc[r] = make_float4(0.f, 0.f, 0.f, 0.f);

  for (int kt = 0; kt < K; kt += 64) {
    __syncthreads();
#pragma unroll
    for (int l = 0; l < 4; ++l) {
      int idx = t + l * 256;
      int node = idx >> 4;
      int kq = idx & 15;
      int gn = n0 + node;
      float4 v = make_float4(0.f, 0.f, 0.f, 0.f);
      if (gn < N) v = *(const float4*)(X + (size_t)gn * K + kt + 4 * kq);
      int kb = 4 * kq;
      Xl[(kb + 0) * 68 + node] = v.x;
      Xl[(kb + 1) * 68 + node] = v.y;
      Xl[(kb + 2) * 68 + node] = v.z;
      Xl[(kb + 3) * 68 + node] = v.w;
    }
#pragma unroll
    for (int l = 0; l < 4; ++l) {
      int idx = t + l * 256;
      ((float4*)Wl)[idx] = *(const float4*)(W + (size_t)(kt + (idx >> 4)) * 64 + 4 * (idx & 15));
    }
    __syncthreads();
#pragma unroll 8
    for (int k = 0; k < 64; ++k) {
      float4 xv = *(const float4*)(Xl + k * 68 + 4 * ty);
      float4 wv = *(const float4*)(Wl + k * 64 + 4 * tx);
      acc[0].x += xv.x * wv.x; acc[0].y += xv.x * wv.y; acc[0].z += xv.x * wv.z; acc[0].w += xv.x * wv.w;
      acc[1].x += xv.y * wv.x; acc[1].y += xv.y * wv.y; acc[1].z += xv.y * wv.z; acc[1].w += xv.y * wv.w;
      acc[2].x += xv.z * wv.x; acc[2].y += xv.z * wv.y; acc[2].z += xv.z * wv.z; acc[2].w += xv.z * wv.w;
      acc[3].x += xv.w * wv.x; acc[3].y += xv.w * wv.y; acc[3].z += xv.w * wv.z; acc[3].w += xv.w * wv.w;
    }
  }
#pragma unroll
  for (int r = 0; r < 4; ++r) {
    int gn = n0 + 4 * ty + r;
    if (gn < N) *(float4*)(H + (size_t)gn * 64 + 4 * tx) = acc[r];
  }
}

// ---------------- CSR aggregation, 4-way MLP unroll ----------------
// out[d] = dinv[d]*sum(val*h[src]) + dinv[d]^2*h[d] + b
// 16-lane group per dst; edge loop unrolled x4 with independent accumulators so
// 4 gathers are in flight per group (r7: serial loop was latency-bound, VALU 12%).
__launch_bounds__(256)
__global__ void k_agg(const float* __restrict__ hin, float* __restrict__ hout,
                      const float* __restrict__ bias, const float* __restrict__ dinv,
                      const int* __restrict__ rowstart,
                      const unsigned long long* __restrict__ colval,
                      int N, int apply_lrelu) {
  const int t = threadIdx.x;
  const int grp = t >> 4;
  const int lane = t & 15;
  const int d = blockIdx.x * 16 + grp;
  if (d >= N) return;
  const int r0 = rowstart[d];
  const int r1 = rowstart[d + 1];
  float4 a0 = make_float4(0.f, 0.f, 0.f, 0.f);
  float4 a1 = make_float4(0.f, 0.f, 0.f, 0.f);
  float4 a2 = make_float4(0.f, 0.f, 0.f, 0.f);
  float4 a3 = make_float4(0.f, 0.f, 0.f, 0.f);
  int r = r0;
  for (; r + 4 <= r1; r += 4) {
    unsigned long long cv0 = colval[r + 0];
    unsigned long long cv1 = colval[r + 1];
    unsigned long long cv2 = colval[r + 2];
    unsigned long long cv3 = colval[r + 3];
    float4 h0 = *(const float4*)(hin + ((size_t)(cv0 >> 32)) * 64 + lane * 4);
    float4 h1 = *(const float4*)(hin + ((size_t)(cv1 >> 32)) * 64 + lane * 4);
    float4 h2 = *(const float4*)(hin + ((size_t)(cv2 >> 32)) * 64 + lane * 4);
    float4 h3 = *(const float4*)(hin + ((size_t)(cv3 >> 32)) * 64 + lane * 4);
    float v0 = __uint_as_float((unsigned int)cv0);
    float v1 = __uint_as_float((unsigned int)cv1);
    float v2 = __uint_as_float((unsigned int)cv2);
    float v3 = __uint_as_float((unsigned int)cv3);
    a0.x += v0 * h0.x; a0.y += v0 * h0.y; a0.z += v0 * h0.z; a0.w += v0 * h0.w;
    a1.x += v1 * h1.x; a1.y += v1 * h1.y; a1.z += v1 * h1.z; a1.w += v1 * h1.w;
    a2.x += v2 * h2.x; a2.y += v2 * h2.y; a2.z += v2 * h2.z; a2.w += v2 * h2.w;
    a3.x += v3 * h3.x; a3.y += v3 * h3.y; a3.z += v3 * h3.z; a3.w += v3 * h3.w;
  }
  for (; r < r1; ++r) {
    unsigned long long cv = colval[r];
    float v = __uint_as_float((unsigned int)cv);
    float4 hv = *(const float4*)(hin + ((size_t)(cv >> 32)) * 64 + lane * 4);
    a0.x += v * hv.x; a0.y += v * hv.y; a0.z += v * hv.z; a0.w += v * hv.w;
  }
  float4 acc;
  acc.x = (a0.x + a1.x) + (a2.x + a3.x);
  acc.y = (a0.y + a1.y) + (a2.y + a3.y);
  acc.z = (a0.z + a1.z) + (a2.z + a3.z);
  acc.w = (a0.w + a1.w) + (a2.w + a3.w);
  float di = dinv[d];
  float di2 = di * di;
  float4 hd = *(const float4*)(hin + (size_t)d * 64 + lane * 4);
  float4 b4 = *(const float4*)(bias + lane * 4);
  float4 o;
  o.x = di * acc.x + di2 * hd.x + b4.x;
  o.y = di * acc.y + di2 * hd.y + b4.y;
  o.z = di * acc.z + di2 * hd.z + b4.z;
  o.w = di * acc.w + di2 * hd.w + b4.w;
  if (apply_lrelu) {
    o.x = (o.x > 0.f) ? o.x : LRELU_SLOPE * o.x;
    o.y = (o.y > 0.f) ? o.y : LRELU_SLOPE * o.y;
    o.z = (o.z > 0.f) ? o.z : LRELU_SLOPE * o.z;
    o.w = (o.w > 0.f) ? o.w : LRELU_SLOPE * o.w;
  }
  *(float4*)(hout + (size_t)d * 64 + lane * 4) = o;
}

// ---------------- BN column stats: per-block partials (atomic-free) ----------------
__launch_bounds__(256)
__global__ void k_stats(const float* __restrict__ h, float* __restrict__ partial, int N) {
  __shared__ float ls[256], lss[256];
  const int t = threadIdx.x;
  const int c = t & 63;
  float a = 0.f, a2 = 0.f;
  for (int n = blockIdx.x * 4 + (t >> 6); n < N; n += gridDim.x * 4) {
    float v = h[(size_t)n * 64 + c];
    a += v;
    a2 += v * v;
  }
  ls[t] = a;
  lss[t] = a2;
  __syncthreads();
  if (t < 64) {
    a = ls[t] + ls[t + 64] + ls[t + 128] + ls[t + 192];
    a2 = lss[t] + lss[t + 64] + lss[t + 128] + lss[t + 192];
    partial[blockIdx.x * 128 + t] = a;
    partial[blockIdx.x * 128 + 64 + t] = a2;
  }
}

__global__ void k_stats_reduce(const float* __restrict__ partial, float* __restrict__ s,
                               float* __restrict__ ss, int nb) {
  int t = threadIdx.x;  // 128 threads
  float a = 0.f;
  for (int b = 0; b < nb; ++b) a += partial[b * 128 + t];
  if (t < 64) s[t] = a;
  else ss[t - 64] = a;
}

// ---------------- BN apply + LeakyReLU ----------------
__launch_bounds__(256)
__global__ void k_bnapply(const float* __restrict__ hin, float* __restrict__ hout,
                          const float* __restrict__ s, const float* __restrict__ ss,
                          const float* __restrict__ g, const float* __restrict__ be,
                          int N) {
  int i = blockIdx.x * blockDim.x + threadIdx.x;  // index over N*16 float4s
  if (i >= N * 16) return;
  int c0 = (i & 15) * 4;
  float invN = 1.0f / (float)N;
  float4 v = ((const float4*)hin)[i];
  float o[4] = {v.x, v.y, v.z, v.w};
#pragma unroll
  for (int k = 0; k < 4; ++k) {
    int c = c0 + k;
    float mean = s[c] * invN;
    float var = ss[c] * invN - mean * mean;
    float scale = g[c] * rsqrtf(var + BN_EPS);
    float r = (o[k] - mean) * scale + be[c];
    o[k] = (r > 0.f) ? r : LRELU_SLOPE * r;
  }
  ((float4*)hout)[i] = make_float4(o[0], o[1], o[2], o[3]);
}

// ---------------- graph boundaries from sorted batch (atomic-free) ----------------
__global__ void k_gbounds(const int* __restrict__ batch, int* __restrict__ gstart,
                          int N, int G) {
  int i = blockIdx.x * blockDim.x + threadIdx.x;
  if (i >= N) return;
  int b = batch[i];
  int prev = (i == 0) ? -1 : batch[i - 1];
  for (int g = prev + 1; g <= b; ++g) gstart[g] = i;   // batch sorted => prev <= b
  if (i == N - 1) {
    for (int g = b + 1; g <= G; ++g) gstart[g] = N;
  }
}

// ---------------- pooling (max & mean per graph) + FC, fused ----------------
__launch_bounds__(256)
__global__ void k_pool(const float* __restrict__ h, const int* __restrict__ gstart,
                       const float* __restrict__ Wfc, const float* __restrict__ bfc,
                       float* __restrict__ out, int G) {
  __shared__ float lmx[256], lsm[256], red[128];
  const int g = blockIdx.x;
  const int t = threadIdx.x;
  const int c = t & 63;
  const int sub = t >> 6;
  const int n0 = gstart[g];
  const int n1 = gstart[g + 1];
  float mx = -INFINITY, sm = 0.f;
  for (int n = n0 + sub; n < n1; n += 4) {
    float v = h[(size_t)n * 64 + c];
    mx = fmaxf(mx, v);
    sm += v;
  }
  lmx[t] = mx;
  lsm[t] = sm;
  __syncthreads();
  if (t < 64) {
    mx = fmaxf(fmaxf(lmx[t], lmx[t + 64]), fmaxf(lmx[t + 128], lmx[t + 192]));
    sm = lsm[t] + lsm[t + 64] + lsm[t + 128] + lsm[t + 192];
    float cntf = (float)(n1 - n0);
    float mean = sm / fmaxf(cntf, 1.0f);
    red[t] = mx * Wfc[t];
    red[t + 64] = mean * Wfc[64 + t];
  }
  __syncthreads();
  for (int st = 64; st >= 1; st >>= 1) {
    if (t < st) red[t] += red[t + st];
    __syncthreads();
  }
  if (t == 0) out[g] = red[0] + bfc[0];
}

// ---------------- host launch ----------------
extern "C" void kernel_launch(void* const* d_in, const int* in_sizes, int n_in,
                              void* d_out, int out_size, void* d_ws, size_t ws_size,
                              hipStream_t stream) {
  const float* x = (const float*)d_in[0];
  const int* ei = (const int*)d_in[1];
  const int* batch = (const int*)d_in[2];
  const float* eattr = (const float*)d_in[3];
  const float* W0 = (const float*)d_in[4];
  const float* b0 = (const float*)d_in[5];
  const float* g0 = (const float*)d_in[6];
  const float* be0 = (const float*)d_in[7];
  const float* W1 = (const float*)d_in[8];
  const float* b1 = (const float*)d_in[9];
  const float* g1 = (const float*)d_in[10];
  const float* be1 = (const float*)d_in[11];
  const float* W2 = (const float*)d_in[12];
  const float* b2 = (const float*)d_in[13];
  const float* W3 = (const float*)d_in[14];
  const float* b3 = (const float*)d_in[15];
  const float* Wfc = (const float*)d_in[16];
  const float* bfc = (const float*)d_in[17];
  float* out = (float*)d_out;

  const int N = in_sizes[2];       // batch is [N]
  const int E = in_sizes[3];       // edge_attr is [E]
  const int CIN = in_sizes[0] / N; // 128
  const int G = out_size;          // [G,1]
  const int nbuck = ceil_div(N, 128);
  const int chunk = ceil_div(E, 256);
  const int M = nbuck * 256;       // hist matrix elements

  // workspace carve-up (256B-aligned slices)
  size_t off = 0;
  auto alloc = [&](size_t bytes) -> void* {
    void* p = (char*)d_ws + off;
    off += (bytes + 255) & ~(size_t)255;
    return p;
  };
  int* histT = (int*)alloc((size_t)1024 * 256 * 4);   // raw counts [bucket][block]
  int* histS = (int*)alloc((size_t)1024 * 256 * 4);   // scanned
  int* bsum = (int*)alloc(1024 * 4);
  unsigned long long* bucketed = (unsigned long long*)alloc((size_t)E * 8);
  float* dinv = (float*)alloc((size_t)N * 4);
  int* rowstart = (int*)alloc((size_t)(N + 1) * 4);
  unsigned long long* colval = (unsigned long long*)alloc((size_t)E * 8);
  float* A = (float*)alloc((size_t)N * 64 * 4);
  float* B = (float*)alloc((size_t)N * 64 * 4);
  float* sums = (float*)alloc(256 * 4);   // s0|ss0|s1|ss1
  float* partial = (float*)alloc(256 * 128 * 4);
  int* gstart = (int*)alloc((size_t)(G + 1) * 4);
  (void)ws_size; (void)n_in; (void)CIN;

  // ---- graph structure (layer-invariant, zero device-scope atomics) ----
  b1_hist<<<256, 256, 0, stream>>>(ei, histT, E, chunk, nbuck);
  const int nbs = ceil_div(M, 1024);
  scan1i<<<nbs, 256, 0, stream>>>(histT, histS, bsum, M);
  scan2i<<<1, 256, 0, stream>>>(bsum, nbs);
  scan3i<<<ceil_div(M, 256), 256, 0, stream>>>(histS, bsum, M);
  b3_scatter<<<256, 256, 0, stream>>>(ei, eattr, histS, bucketed, E, chunk, nbuck);
  c1_degree<<<nbuck, 256, 0, stream>>>(bucketed, histS, rowstart, dinv, N, E, nbuck);
  c2_fill<<<nbuck, 256, 0, stream>>>(bucketed, histS, rowstart, dinv, colval, N, E, nbuck);
  k_gbounds<<<ceil_div(N, 256), 256, 0, stream>>>(batch, gstart, N, G);

  // layer 0: gemm(x,W0)->A; agg A->B; stats(B); bn+lrelu B->A
  k_gemm<128><<<ceil_div(N, 64), 256, 0, stream>>>(x, W0, A, N);
  k_agg<<<ceil_div(N, 16), 256, 0, stream>>>(A, B, b0, dinv, rowstart, colval, N, 0);
  k_stats<<<256, 256, 0, stream>>>(B, partial, N);
  k_stats_reduce<<<1, 128, 0, stream>>>(partial, sums + 0, sums + 64, 256);
  k_bnapply<<<ceil_div(N * 16, 256), 256, 0, stream>>>(B, A, sums + 0, sums + 64, g0, be0, N);

  // layer 1: gemm(A,W1)->B; agg B->A; stats(A); bn+lrelu A->B
  k_gemm<64><<<ceil_div(N, 64), 256, 0, stream>>>(A, W1, B, N);
  k_agg<<<ceil_div(N, 16), 256, 0, stream>>>(B, A, b1, dinv, rowstart, colval, N, 0);
  k_stats<<<256, 256, 0, stream>>>(A, partial, N);
  k_stats_reduce<<<1, 128, 0, stream>>>(partial, sums + 128, sums + 192, 256);
  k_bnapply<<<ceil_div(N * 16, 256), 256, 0, stream>>>(A, B, sums + 128, sums + 192, g1, be1, N);

  // layer 2: gemm(B,W2)->A; agg(+lrelu) A->B
  k_gemm<64><<<ceil_div(N, 64), 256, 0, stream>>>(B, W2, A, N);
  k_agg<<<ceil_div(N, 16), 256, 0, stream>>>(A, B, b2, dinv, rowstart, colval, N, 1);

  // layer 3: gemm(B,W3)->A; agg(+lrelu) A->B
  k_gemm<64><<<ceil_div(N, 64), 256, 0, stream>>>(B, W3, A, N);
  k_agg<<<ceil_div(N, 16), 256, 0, stream>>>(A, B, b3, dinv, rowstart, colval, N, 1);

  // pooling + FC
  k_pool<<<G, 256, 0, stream>>>(B, gstart, Wfc, bfc, out, G);
}

// Round 9
// 635.853 us; speedup vs baseline: 1.5633x; 1.1611x over previous
//
#include <hip/hip_runtime.h>
#include <math.h>

#define LRELU_SLOPE 0.01f
#define BN_EPS 1e-5f
#define WQ_SCALE 1048576.0f        /* 2^20 fixed-point for per-dst weighted degree */
#define WQ_INV   9.5367431640625e-7f

static inline int ceil_div(int a, int b) { return (a + b - 1) / b; }

// ============ Phase B1: per-(bucket,block) histogram, bucket = dst>>7 ============
__launch_bounds__(256)
__global__ void b1_hist(const int* __restrict__ ei, int* __restrict__ histT,
                        int E, int chunk, int nbuck) {
  __shared__ unsigned int hist[1024];
  const int t = threadIdx.x;
  const int blk = blockIdx.x;
#pragma unroll
  for (int l = 0; l < 4; ++l) hist[t + l * 256] = 0;
  __syncthreads();
  const int e0 = blk * chunk;
  const int e1 = min(e0 + chunk, E);
  for (int e = e0 + t; e < e1; e += 256) {
    int d = ei[E + e];
    atomicAdd(&hist[d >> 7], 1u);
  }
  __syncthreads();
#pragma unroll
  for (int l = 0; l < 4; ++l) {
    int b = t + l * 256;
    if (b < nbuck) histT[(size_t)b * 256 + blk] = (int)hist[b];
  }
}

// ============ int exclusive scan (2-level), M up to 256*1024 ============
__global__ void scan1i(const int* __restrict__ in, int* __restrict__ out,
                       int* __restrict__ bsum, int n) {
  __shared__ int lds[256];
  const int t = threadIdx.x;
  const int base = blockIdx.x * 1024 + t * 4;
  int v0 = 0, v1 = 0, v2 = 0, v3 = 0;
  if (base + 0 < n) v0 = in[base + 0];
  if (base + 1 < n) v1 = in[base + 1];
  if (base + 2 < n) v2 = in[base + 2];
  if (base + 3 < n) v3 = in[base + 3];
  int s = v0 + v1 + v2 + v3;
  lds[t] = s;
  __syncthreads();
#pragma unroll
  for (int off = 1; off < 256; off <<= 1) {
    int y = 0;
    if (t >= off) y = lds[t - off];
    __syncthreads();
    if (t >= off) lds[t] += y;
    __syncthreads();
  }
  int incl = lds[t];
  int excl = incl - s;
  if (base + 0 < n) out[base + 0] = excl;
  if (base + 1 < n) out[base + 1] = excl + v0;
  if (base + 2 < n) out[base + 2] = excl + v0 + v1;
  if (base + 3 < n) out[base + 3] = excl + v0 + v1 + v2;
  if (t == 255) bsum[blockIdx.x] = incl;
}

__global__ void scan2i(int* __restrict__ bsum, int nb) {  // in-place exclusive, nb<=256
  __shared__ int lds[256];
  int t = threadIdx.x;
  int v = (t < nb) ? bsum[t] : 0;
  lds[t] = v;
  __syncthreads();
#pragma unroll
  for (int off = 1; off < 256; off <<= 1) {
    int y = 0;
    if (t >= off) y = lds[t - off];
    __syncthreads();
    if (t >= off) lds[t] += y;
    __syncthreads();
  }
  if (t < nb) bsum[t] = lds[t] - v;
}

__global__ void scan3i(int* __restrict__ data, const int* __restrict__ bscan, int n) {
  int i = blockIdx.x * blockDim.x + threadIdx.x;
  if (i < n) data[i] += bscan[i >> 10];
}

// ============ Phase B3: scatter edges into bucket-grouped array ============
__launch_bounds__(256)
__global__ void b3_scatter(const int* __restrict__ ei, const float* __restrict__ w,
                           const int* __restrict__ histS,
                           unsigned long long* __restrict__ bucketed,
                           int E, int chunk, int nbuck) {
  __shared__ unsigned int cursor[1024];
  const int t = threadIdx.x;
  const int blk = blockIdx.x;
#pragma unroll
  for (int l = 0; l < 4; ++l) {
    int b = t + l * 256;
    cursor[b] = (b < nbuck) ? (unsigned int)histS[(size_t)b * 256 + blk] : 0u;
  }
  __syncthreads();
  const int e0 = blk * chunk;
  const int e1 = min(e0 + chunk, E);
  for (int e = e0 + t; e < e1; e += 256) {
    int s = ei[e];
    int d = ei[E + e];
    unsigned int pos = atomicAdd(&cursor[d >> 7], 1u);
    unsigned long long p = ((unsigned long long)(unsigned int)(d & 127) << 57) |
                           ((unsigned long long)(unsigned int)s << 32) |
                           (unsigned long long)__float_as_uint(w[e]);
    bucketed[pos] = p;
  }
}

// ============ Phase C1: per-bucket degree + rowstart (LDS only) ============
__launch_bounds__(256)
__global__ void c1_degree(const unsigned long long* __restrict__ bucketed,
                          const int* __restrict__ histS,
                          int* __restrict__ rowstart, float* __restrict__ dinv,
                          int N, int E, int nbuck) {
  __shared__ unsigned int cnt[128], wsum[128];
  __shared__ int sc[128];
  const int t = threadIdx.x;
  const int b = blockIdx.x;
  if (t < 128) { cnt[t] = 0; wsum[t] = 0; }
  __syncthreads();
  const int r0 = histS[(size_t)b * 256];
  const int r1 = (b + 1 < nbuck) ? histS[(size_t)(b + 1) * 256] : E;
  for (int r = r0 + t; r < r1; r += 256) {
    unsigned long long p = bucketed[r];
    int d7 = (int)(p >> 57);
    float wv = __uint_as_float((unsigned int)p);
    atomicAdd(&cnt[d7], 1u);
    atomicAdd(&wsum[d7], (unsigned int)__float2uint_rn(wv * WQ_SCALE));
  }
  __syncthreads();
  if (t < 128) sc[t] = (int)cnt[t];
  __syncthreads();
#pragma unroll
  for (int off = 1; off < 128; off <<= 1) {
    int y = 0;
    if (t < 128 && t >= off) y = sc[t - off];
    __syncthreads();
    if (t < 128 && t >= off) sc[t] += y;
    __syncthreads();
  }
  if (t < 128) {
    int node = (b << 7) + t;
    if (node < N) {
      rowstart[node] = r0 + sc[t] - (int)cnt[t];   // exclusive
      float deg = 1.0f + (float)wsum[t] * WQ_INV;  // self-loop + edge weights
      dinv[node] = rsqrtf(deg);
    }
  }
  if (b == 0 && t == 0) rowstart[N] = E;
}

// ============ Phase C2: per-bucket CSR fill ============
__launch_bounds__(256)
__global__ void c2_fill(const unsigned long long* __restrict__ bucketed,
                        const int* __restrict__ histS,
                        const int* __restrict__ rowstart, const float* __restrict__ dinv,
                        unsigned long long* __restrict__ colval,
                        int N, int E, int nbuck) {
  __shared__ unsigned int cursor[128];
  const int t = threadIdx.x;
  const int b = blockIdx.x;
  if (t < 128) {
    int node = (b << 7) + t;
    cursor[t] = (node < N) ? (unsigned int)rowstart[node] : 0u;
  }
  __syncthreads();
  const int r0 = histS[(size_t)b * 256];
  const int r1 = (b + 1 < nbuck) ? histS[(size_t)(b + 1) * 256] : E;
  for (int r = r0 + t; r < r1; r += 256) {
    unsigned long long p = bucketed[r];
    int d7 = (int)(p >> 57);
    int s = (int)((p >> 32) & 0x1FFFFFF);
    float wv = __uint_as_float((unsigned int)p);
    unsigned int pos = atomicAdd(&cursor[d7], 1u);
    float v = wv * dinv[s];
    colval[pos] = ((unsigned long long)(unsigned int)s << 32) |
                  (unsigned long long)__float_as_uint(v);
  }
}

// ---------------- GEMM: H[N,64] = X[N,K] @ W[K,64]  (fp32, VALU) ----------------
template <int K>
__launch_bounds__(256, 4)
__global__ void k_gemm(const float* __restrict__ X, const float* __restrict__ W,
                       float* __restrict__ H, int N) {
  __shared__ float Xl[64 * 68];
  __shared__ float Wl[64 * 64];
  const int t = threadIdx.x;
  const int tx = t & 15;
  const int ty = t >> 4;
  const int n0 = blockIdx.x * 64;

  float4 acc[4];
#pragma unroll
  for (int r = 0; r < 4; ++r) acc[r] = make_float4(0.f, 0.f, 0.f, 0.f);

  for (int kt = 0; kt < K; kt += 64) {
    __syncthreads();
#pragma unroll
    for (int l = 0; l < 4; ++l) {
      int idx = t + l * 256;
      int node = idx >> 4;
      int kq = idx & 15;
      int gn = n0 + node;
      float4 v = make_float4(0.f, 0.f, 0.f, 0.f);
      if (gn < N) v = *(const float4*)(X + (size_t)gn * K + kt + 4 * kq);
      int kb = 4 * kq;
      Xl[(kb + 0) * 68 + node] = v.x;
      Xl[(kb + 1) * 68 + node] = v.y;
      Xl[(kb + 2) * 68 + node] = v.z;
      Xl[(kb + 3) * 68 + node] = v.w;
    }
#pragma unroll
    for (int l = 0; l < 4; ++l) {
      int idx = t + l * 256;
      ((float4*)Wl)[idx] = *(const float4*)(W + (size_t)(kt + (idx >> 4)) * 64 + 4 * (idx & 15));
    }
    __syncthreads();
#pragma unroll 8
    for (int k = 0; k < 64; ++k) {
      float4 xv = *(const float4*)(Xl + k * 68 + 4 * ty);
      float4 wv = *(const float4*)(Wl + k * 64 + 4 * tx);
      acc[0].x += xv.x * wv.x; acc[0].y += xv.x * wv.y; acc[0].z += xv.x * wv.z; acc[0].w += xv.x * wv.w;
      acc[1].x += xv.y * wv.x; acc[1].y += xv.y * wv.y; acc[1].z += xv.y * wv.z; acc[1].w += xv.y * wv.w;
      acc[2].x += xv.z * wv.x; acc[2].y += xv.z * wv.y; acc[2].z += xv.z * wv.z; acc[2].w += xv.z * wv.w;
      acc[3].x += xv.w * wv.x; acc[3].y += xv.w * wv.y; acc[3].z += xv.w * wv.z; acc[3].w += xv.w * wv.w;
    }
  }
#pragma unroll
  for (int r = 0; r < 4; ++r) {
    int gn = n0 + 4 * ty + r;
    if (gn < N) *(float4*)(H + (size_t)gn * 64 + 4 * tx) = acc[r];
  }
}

// ---------------- CSR aggregation, 8-way MLP unroll ----------------
// out[d] = dinv[d]*sum(val*h[src]) + dinv[d]^2*h[d] + b
// 16-lane group per dst; 8 independent gathers in flight (r8: 4-wide gave 62us,
// still latency-limited with VALU 14%).
__launch_bounds__(256)
__global__ void k_agg(const float* __restrict__ hin, float* __restrict__ hout,
                      const float* __restrict__ bias, const float* __restrict__ dinv,
                      const int* __restrict__ rowstart,
                      const unsigned long long* __restrict__ colval,
                      int N, int apply_lrelu) {
  const int t = threadIdx.x;
  const int grp = t >> 4;
  const int lane = t & 15;
  const int d = blockIdx.x * 16 + grp;
  if (d >= N) return;
  const int r0 = rowstart[d];
  const int r1 = rowstart[d + 1];
  float4 a0 = make_float4(0.f, 0.f, 0.f, 0.f);
  float4 a1 = make_float4(0.f, 0.f, 0.f, 0.f);
  float4 a2 = make_float4(0.f, 0.f, 0.f, 0.f);
  float4 a3 = make_float4(0.f, 0.f, 0.f, 0.f);
  int r = r0;
  for (; r + 8 <= r1; r += 8) {
    unsigned long long cv0 = colval[r + 0];
    unsigned long long cv1 = colval[r + 1];
    unsigned long long cv2 = colval[r + 2];
    unsigned long long cv3 = colval[r + 3];
    unsigned long long cv4 = colval[r + 4];
    unsigned long long cv5 = colval[r + 5];
    unsigned long long cv6 = colval[r + 6];
    unsigned long long cv7 = colval[r + 7];
    float4 h0 = *(const float4*)(hin + ((size_t)(cv0 >> 32)) * 64 + lane * 4);
    float4 h1 = *(const float4*)(hin + ((size_t)(cv1 >> 32)) * 64 + lane * 4);
    float4 h2 = *(const float4*)(hin + ((size_t)(cv2 >> 32)) * 64 + lane * 4);
    float4 h3 = *(const float4*)(hin + ((size_t)(cv3 >> 32)) * 64 + lane * 4);
    float4 h4 = *(const float4*)(hin + ((size_t)(cv4 >> 32)) * 64 + lane * 4);
    float4 h5 = *(const float4*)(hin + ((size_t)(cv5 >> 32)) * 64 + lane * 4);
    float4 h6 = *(const float4*)(hin + ((size_t)(cv6 >> 32)) * 64 + lane * 4);
    float4 h7 = *(const float4*)(hin + ((size_t)(cv7 >> 32)) * 64 + lane * 4);
    float v0 = __uint_as_float((unsigned int)cv0);
    float v1 = __uint_as_float((unsigned int)cv1);
    float v2 = __uint_as_float((unsigned int)cv2);
    float v3 = __uint_as_float((unsigned int)cv3);
    float v4 = __uint_as_float((unsigned int)cv4);
    float v5 = __uint_as_float((unsigned int)cv5);
    float v6 = __uint_as_float((unsigned int)cv6);
    float v7 = __uint_as_float((unsigned int)cv7);
    a0.x += v0 * h0.x; a0.y += v0 * h0.y; a0.z += v0 * h0.z; a0.w += v0 * h0.w;
    a1.x += v1 * h1.x; a1.y += v1 * h1.y; a1.z += v1 * h1.z; a1.w += v1 * h1.w;
    a2.x += v2 * h2.x; a2.y += v2 * h2.y; a2.z += v2 * h2.z; a2.w += v2 * h2.w;
    a3.x += v3 * h3.x; a3.y += v3 * h3.y; a3.z += v3 * h3.z; a3.w += v3 * h3.w;
    a0.x += v4 * h4.x; a0.y += v4 * h4.y; a0.z += v4 * h4.z; a0.w += v4 * h4.w;
    a1.x += v5 * h5.x; a1.y += v5 * h5.y; a1.z += v5 * h5.z; a1.w += v5 * h5.w;
    a2.x += v6 * h6.x; a2.y += v6 * h6.y; a2.z += v6 * h6.z; a2.w += v6 * h6.w;
    a3.x += v7 * h7.x; a3.y += v7 * h7.y; a3.z += v7 * h7.z; a3.w += v7 * h7.w;
  }
  for (; r + 4 <= r1; r += 4) {
    unsigned long long cv0 = colval[r + 0];
    unsigned long long cv1 = colval[r + 1];
    unsigned long long cv2 = colval[r + 2];
    unsigned long long cv3 = colval[r + 3];
    float4 h0 = *(const float4*)(hin + ((size_t)(cv0 >> 32)) * 64 + lane * 4);
    float4 h1 = *(const float4*)(hin + ((size_t)(cv1 >> 32)) * 64 + lane * 4);
    float4 h2 = *(const float4*)(hin + ((size_t)(cv2 >> 32)) * 64 + lane * 4);
    float4 h3 = *(const float4*)(hin + ((size_t)(cv3 >> 32)) * 64 + lane * 4);
    float v0 = __uint_as_float((unsigned int)cv0);
    float v1 = __uint_as_float((unsigned int)cv1);
    float v2 = __uint_as_float((unsigned int)cv2);
    float v3 = __uint_as_float((unsigned int)cv3);
    a0.x += v0 * h0.x; a0.y += v0 * h0.y; a0.z += v0 * h0.z; a0.w += v0 * h0.w;
    a1.x += v1 * h1.x; a1.y += v1 * h1.y; a1.z += v1 * h1.z; a1.w += v1 * h1.w;
    a2.x += v2 * h2.x; a2.y += v2 * h2.y; a2.z += v2 * h2.z; a2.w += v2 * h2.w;
    a3.x += v3 * h3.x; a3.y += v3 * h3.y; a3.z += v3 * h3.z; a3.w += v3 * h3.w;
  }
  for (; r < r1; ++r) {
    unsigned long long cv = colval[r];
    float v = __uint_as_float((unsigned int)cv);
    float4 hv = *(const float4*)(hin + ((size_t)(cv >> 32)) * 64 + lane * 4);
    a0.x += v * hv.x; a0.y += v * hv.y; a0.z += v * hv.z; a0.w += v * hv.w;
  }
  float4 acc;
  acc.x = (a0.x + a1.x) + (a2.x + a3.x);
  acc.y = (a0.y + a1.y) + (a2.y + a3.y);
  acc.z = (a0.z + a1.z) + (a2.z + a3.z);
  acc.w = (a0.w + a1.w) + (a2.w + a3.w);
  float di = dinv[d];
  float di2 = di * di;
  float4 hd = *(const float4*)(hin + (size_t)d * 64 + lane * 4);
  float4 b4 = *(const float4*)(bias + lane * 4);
  float4 o;
  o.x = di * acc.x + di2 * hd.x + b4.x;
  o.y = di * acc.y + di2 * hd.y + b4.y;
  o.z = di * acc.z + di2 * hd.z + b4.z;
  o.w = di * acc.w + di2 * hd.w + b4.w;
  if (apply_lrelu) {
    o.x = (o.x > 0.f) ? o.x : LRELU_SLOPE * o.x;
    o.y = (o.y > 0.f) ? o.y : LRELU_SLOPE * o.y;
    o.z = (o.z > 0.f) ? o.z : LRELU_SLOPE * o.z;
    o.w = (o.w > 0.f) ? o.w : LRELU_SLOPE * o.w;
  }
  *(float4*)(hout + (size_t)d * 64 + lane * 4) = o;
}

// ---------------- BN column stats: per-block partials (atomic-free) ----------------
__launch_bounds__(256)
__global__ void k_stats(const float* __restrict__ h, float* __restrict__ partial, int N) {
  __shared__ float ls[256], lss[256];
  const int t = threadIdx.x;
  const int c = t & 63;
  float a = 0.f, a2 = 0.f;
  for (int n = blockIdx.x * 4 + (t >> 6); n < N; n += gridDim.x * 4) {
    float v = h[(size_t)n * 64 + c];
    a += v;
    a2 += v * v;
  }
  ls[t] = a;
  lss[t] = a2;
  __syncthreads();
  if (t < 64) {
    a = ls[t] + ls[t + 64] + ls[t + 128] + ls[t + 192];
    a2 = lss[t] + lss[t + 64] + lss[t + 128] + lss[t + 192];
    partial[blockIdx.x * 128 + t] = a;
    partial[blockIdx.x * 128 + 64 + t] = a2;
  }
}

// Parallel reduce: 128 blocks (one per output column), 256 threads each.
// r8: the old 1-block serial loop was 62us (load->add chain at L2 latency).
__global__ void k_stats_reduce(const float* __restrict__ partial, float* __restrict__ s,
                               float* __restrict__ ss, int nb) {
  __shared__ float red[256];
  const int c = blockIdx.x;   // 0..127
  const int t = threadIdx.x;  // 0..255
  float a = 0.f;
  for (int b = t; b < nb; b += 256) a += partial[(size_t)b * 128 + c];
  red[t] = a;
  __syncthreads();
  for (int st = 128; st >= 1; st >>= 1) {
    if (t < st) red[t] += red[t + st];
    __syncthreads();
  }
  if (t == 0) {
    if (c < 64) s[c] = red[0];
    else ss[c - 64] = red[0];
  }
}

// ---------------- BN apply + LeakyReLU ----------------
__launch_bounds__(256)
__global__ void k_bnapply(const float* __restrict__ hin, float* __restrict__ hout,
                          const float* __restrict__ s, const float* __restrict__ ss,
                          const float* __restrict__ g, const float* __restrict__ be,
                          int N) {
  int i = blockIdx.x * blockDim.x + threadIdx.x;  // index over N*16 float4s
  if (i >= N * 16) return;
  int c0 = (i & 15) * 4;
  float invN = 1.0f / (float)N;
  float4 v = ((const float4*)hin)[i];
  float o[4] = {v.x, v.y, v.z, v.w};
#pragma unroll
  for (int k = 0; k < 4; ++k) {
    int c = c0 + k;
    float mean = s[c] * invN;
    float var = ss[c] * invN - mean * mean;
    float scale = g[c] * rsqrtf(var + BN_EPS);
    float r = (o[k] - mean) * scale + be[c];
    o[k] = (r > 0.f) ? r : LRELU_SLOPE * r;
  }
  ((float4*)hout)[i] = make_float4(o[0], o[1], o[2], o[3]);
}

// ---------------- graph boundaries from sorted batch (atomic-free) ----------------
__global__ void k_gbounds(const int* __restrict__ batch, int* __restrict__ gstart,
                          int N, int G) {
  int i = blockIdx.x * blockDim.x + threadIdx.x;
  if (i >= N) return;
  int b = batch[i];
  int prev = (i == 0) ? -1 : batch[i - 1];
  for (int g = prev + 1; g <= b; ++g) gstart[g] = i;   // batch sorted => prev <= b
  if (i == N - 1) {
    for (int g = b + 1; g <= G; ++g) gstart[g] = N;
  }
}

// ---------------- pooling (max & mean per graph) + FC, fused ----------------
__launch_bounds__(256)
__global__ void k_pool(const float* __restrict__ h, const int* __restrict__ gstart,
                       const float* __restrict__ Wfc, const float* __restrict__ bfc,
                       float* __restrict__ out, int G) {
  __shared__ float lmx[256], lsm[256], red[128];
  const int g = blockIdx.x;
  const int t = threadIdx.x;
  const int c = t & 63;
  const int sub = t >> 6;
  const int n0 = gstart[g];
  const int n1 = gstart[g + 1];
  float mx = -INFINITY, sm = 0.f;
  for (int n = n0 + sub; n < n1; n += 4) {
    float v = h[(size_t)n * 64 + c];
    mx = fmaxf(mx, v);
    sm += v;
  }
  lmx[t] = mx;
  lsm[t] = sm;
  __syncthreads();
  if (t < 64) {
    mx = fmaxf(fmaxf(lmx[t], lmx[t + 64]), fmaxf(lmx[t + 128], lmx[t + 192]));
    sm = lsm[t] + lsm[t + 64] + lsm[t + 128] + lsm[t + 192];
    float cntf = (float)(n1 - n0);
    float mean = sm / fmaxf(cntf, 1.0f);
    red[t] = mx * Wfc[t];
    red[t + 64] = mean * Wfc[64 + t];
  }
  __syncthreads();
  for (int st = 64; st >= 1; st >>= 1) {
    if (t < st) red[t] += red[t + st];
    __syncthreads();
  }
  if (t == 0) out[g] = red[0] + bfc[0];
}

// ---------------- host launch ----------------
extern "C" void kernel_launch(void* const* d_in, const int* in_sizes, int n_in,
                              void* d_out, int out_size, void* d_ws, size_t ws_size,
                              hipStream_t stream) {
  const float* x = (const float*)d_in[0];
  const int* ei = (const int*)d_in[1];
  const int* batch = (const int*)d_in[2];
  const float* eattr = (const float*)d_in[3];
  const float* W0 = (const float*)d_in[4];
  const float* b0 = (const float*)d_in[5];
  const float* g0 = (const float*)d_in[6];
  const float* be0 = (const float*)d_in[7];
  const float* W1 = (const float*)d_in[8];
  const float* b1 = (const float*)d_in[9];
  const float* g1 = (const float*)d_in[10];
  const float* be1 = (const float*)d_in[11];
  const float* W2 = (const float*)d_in[12];
  const float* b2 = (const float*)d_in[13];
  const float* W3 = (const float*)d_in[14];
  const float* b3 = (const float*)d_in[15];
  const float* Wfc = (const float*)d_in[16];
  const float* bfc = (const float*)d_in[17];
  float* out = (float*)d_out;

  const int N = in_sizes[2];       // batch is [N]
  const int E = in_sizes[3];       // edge_attr is [E]
  const int CIN = in_sizes[0] / N; // 128
  const int G = out_size;          // [G,1]
  const int nbuck = ceil_div(N, 128);
  const int chunk = ceil_div(E, 256);
  const int M = nbuck * 256;       // hist matrix elements

  // workspace carve-up (256B-aligned slices)
  size_t off = 0;
  auto alloc = [&](size_t bytes) -> void* {
    void* p = (char*)d_ws + off;
    off += (bytes + 255) & ~(size_t)255;
    return p;
  };
  int* histT = (int*)alloc((size_t)1024 * 256 * 4);   // raw counts [bucket][block]
  int* histS = (int*)alloc((size_t)1024 * 256 * 4);   // scanned
  int* bsum = (int*)alloc(1024 * 4);
  unsigned long long* bucketed = (unsigned long long*)alloc((size_t)E * 8);
  float* dinv = (float*)alloc((size_t)N * 4);
  int* rowstart = (int*)alloc((size_t)(N + 1) * 4);
  unsigned long long* colval = (unsigned long long*)alloc((size_t)E * 8);
  float* A = (float*)alloc((size_t)N * 64 * 4);
  float* B = (float*)alloc((size_t)N * 64 * 4);
  float* sums = (float*)alloc(256 * 4);   // s0|ss0|s1|ss1
  float* partial = (float*)alloc(256 * 128 * 4);
  int* gstart = (int*)alloc((size_t)(G + 1) * 4);
  (void)ws_size; (void)n_in; (void)CIN;

  // ---- graph structure (layer-invariant, zero device-scope atomics) ----
  b1_hist<<<256, 256, 0, stream>>>(ei, histT, E, chunk, nbuck);
  const int nbs = ceil_div(M, 1024);
  scan1i<<<nbs, 256, 0, stream>>>(histT, histS, bsum, M);
  scan2i<<<1, 256, 0, stream>>>(bsum, nbs);
  scan3i<<<ceil_div(M, 256), 256, 0, stream>>>(histS, bsum, M);
  b3_scatter<<<256, 256, 0, stream>>>(ei, eattr, histS, bucketed, E, chunk, nbuck);
  c1_degree<<<nbuck, 256, 0, stream>>>(bucketed, histS, rowstart, dinv, N, E, nbuck);
  c2_fill<<<nbuck, 256, 0, stream>>>(bucketed, histS, rowstart, dinv, colval, N, E, nbuck);
  k_gbounds<<<ceil_div(N, 256), 256, 0, stream>>>(batch, gstart, N, G);

  // layer 0: gemm(x,W0)->A; agg A->B; stats(B); bn+lrelu B->A
  k_gemm<128><<<ceil_div(N, 64), 256, 0, stream>>>(x, W0, A, N);
  k_agg<<<ceil_div(N, 16), 256, 0, stream>>>(A, B, b0, dinv, rowstart, colval, N, 0);
  k_stats<<<256, 256, 0, stream>>>(B, partial, N);
  k_stats_reduce<<<128, 256, 0, stream>>>(partial, sums + 0, sums + 64, 256);
  k_bnapply<<<ceil_div(N * 16, 256), 256, 0, stream>>>(B, A, sums + 0, sums + 64, g0, be0, N);

  // layer 1: gemm(A,W1)->B; agg B->A; stats(A); bn+lrelu A->B
  k_gemm<64><<<ceil_div(N, 64), 256, 0, stream>>>(A, W1, B, N);
  k_agg<<<ceil_div(N, 16), 256, 0, stream>>>(B, A, b1, dinv, rowstart, colval, N, 0);
  k_stats<<<256, 256, 0, stream>>>(A, partial, N);
  k_stats_reduce<<<128, 256, 0, stream>>>(partial, sums + 128, sums + 192, 256);
  k_bnapply<<<ceil_div(N * 16, 256), 256, 0, stream>>>(A, B, sums + 128, sums + 192, g1, be1, N);

  // layer 2: gemm(B,W2)->A; agg(+lrelu) A->B
  k_gemm<64><<<ceil_div(N, 64), 256, 0, stream>>>(B, W2, A, N);
  k_agg<<<ceil_div(N, 16), 256, 0, stream>>>(A, B, b2, dinv, rowstart, colval, N, 1);

  // layer 3: gemm(B,W3)->A; agg(+lrelu) A->B
  k_gemm<64><<<ceil_div(N, 64), 256, 0, stream>>>(B, W3, A, N);
  k_agg<<<ceil_div(N, 16), 256, 0, stream>>>(A, B, b3, dinv, rowstart, colval, N, 1);

  // pooling + FC
  k_pool<<<G, 256, 0, stream>>>(B, gstart, Wfc, bfc, out, G);
}

// Round 10
// 539.002 us; speedup vs baseline: 1.8442x; 1.1797x over previous
//
#include <hip/hip_runtime.h>
#include <math.h>

#define LRELU_SLOPE 0.01f
#define BN_EPS 1e-5f
#define WQ_SCALE 1048576.0f        /* 2^20 fixed-point for per-dst weighted degree */
#define WQ_INV   9.5367431640625e-7f

static inline int ceil_div(int a, int b) { return (a + b - 1) / b; }

// bf16 helpers: storage is high 16 bits of fp32, RNE rounding on store.
__device__ __forceinline__ unsigned short f2bf(float f) {
  unsigned int u = __float_as_uint(f);
  u = u + 0x7FFFu + ((u >> 16) & 1u);
  return (unsigned short)(u >> 16);
}
#define BF2F(u) __uint_as_float(((unsigned int)(u)) << 16)

// ============ Phase B1: per-(bucket,block) histogram, bucket = dst>>7 ============
__launch_bounds__(256)
__global__ void b1_hist(const int* __restrict__ ei, int* __restrict__ histT,
                        int E, int chunk, int nbuck) {
  __shared__ unsigned int hist[1024];
  const int t = threadIdx.x;
  const int blk = blockIdx.x;
#pragma unroll
  for (int l = 0; l < 4; ++l) hist[t + l * 256] = 0;
  __syncthreads();
  const int e0 = blk * chunk;
  const int e1 = min(e0 + chunk, E);
  for (int e = e0 + t; e < e1; e += 256) {
    int d = ei[E + e];
    atomicAdd(&hist[d >> 7], 1u);
  }
  __syncthreads();
#pragma unroll
  for (int l = 0; l < 4; ++l) {
    int b = t + l * 256;
    if (b < nbuck) histT[(size_t)b * 256 + blk] = (int)hist[b];
  }
}

// ============ int exclusive scan (2-level), M up to 256*1024 ============
__global__ void scan1i(const int* __restrict__ in, int* __restrict__ out,
                       int* __restrict__ bsum, int n) {
  __shared__ int lds[256];
  const int t = threadIdx.x;
  const int base = blockIdx.x * 1024 + t * 4;
  int v0 = 0, v1 = 0, v2 = 0, v3 = 0;
  if (base + 0 < n) v0 = in[base + 0];
  if (base + 1 < n) v1 = in[base + 1];
  if (base + 2 < n) v2 = in[base + 2];
  if (base + 3 < n) v3 = in[base + 3];
  int s = v0 + v1 + v2 + v3;
  lds[t] = s;
  __syncthreads();
#pragma unroll
  for (int off = 1; off < 256; off <<= 1) {
    int y = 0;
    if (t >= off) y = lds[t - off];
    __syncthreads();
    if (t >= off) lds[t] += y;
    __syncthreads();
  }
  int incl = lds[t];
  int excl = incl - s;
  if (base + 0 < n) out[base + 0] = excl;
  if (base + 1 < n) out[base + 1] = excl + v0;
  if (base + 2 < n) out[base + 2] = excl + v0 + v1;
  if (base + 3 < n) out[base + 3] = excl + v0 + v1 + v2;
  if (t == 255) bsum[blockIdx.x] = incl;
}

__global__ void scan2i(int* __restrict__ bsum, int nb) {  // in-place exclusive, nb<=256
  __shared__ int lds[256];
  int t = threadIdx.x;
  int v = (t < nb) ? bsum[t] : 0;
  lds[t] = v;
  __syncthreads();
#pragma unroll
  for (int off = 1; off < 256; off <<= 1) {
    int y = 0;
    if (t >= off) y = lds[t - off];
    __syncthreads();
    if (t >= off) lds[t] += y;
    __syncthreads();
  }
  if (t < nb) bsum[t] = lds[t] - v;
}

__global__ void scan3i(int* __restrict__ data, const int* __restrict__ bscan, int n) {
  int i = blockIdx.x * blockDim.x + threadIdx.x;
  if (i < n) data[i] += bscan[i >> 10];
}

// ============ Phase B3: scatter edges into bucket-grouped array ============
__launch_bounds__(256)
__global__ void b3_scatter(const int* __restrict__ ei, const float* __restrict__ w,
                           const int* __restrict__ histS,
                           unsigned long long* __restrict__ bucketed,
                           int E, int chunk, int nbuck) {
  __shared__ unsigned int cursor[1024];
  const int t = threadIdx.x;
  const int blk = blockIdx.x;
#pragma unroll
  for (int l = 0; l < 4; ++l) {
    int b = t + l * 256;
    cursor[b] = (b < nbuck) ? (unsigned int)histS[(size_t)b * 256 + blk] : 0u;
  }
  __syncthreads();
  const int e0 = blk * chunk;
  const int e1 = min(e0 + chunk, E);
  for (int e = e0 + t; e < e1; e += 256) {
    int s = ei[e];
    int d = ei[E + e];
    unsigned int pos = atomicAdd(&cursor[d >> 7], 1u);
    unsigned long long p = ((unsigned long long)(unsigned int)(d & 127) << 57) |
                           ((unsigned long long)(unsigned int)s << 32) |
                           (unsigned long long)__float_as_uint(w[e]);
    bucketed[pos] = p;
  }
}

// ============ Phase C1: per-bucket degree + rowstart (LDS only) ============
__launch_bounds__(256)
__global__ void c1_degree(const unsigned long long* __restrict__ bucketed,
                          const int* __restrict__ histS,
                          int* __restrict__ rowstart, float* __restrict__ dinv,
                          int N, int E, int nbuck) {
  __shared__ unsigned int cnt[128], wsum[128];
  __shared__ int sc[128];
  const int t = threadIdx.x;
  const int b = blockIdx.x;
  if (t < 128) { cnt[t] = 0; wsum[t] = 0; }
  __syncthreads();
  const int r0 = histS[(size_t)b * 256];
  const int r1 = (b + 1 < nbuck) ? histS[(size_t)(b + 1) * 256] : E;
  for (int r = r0 + t; r < r1; r += 256) {
    unsigned long long p = bucketed[r];
    int d7 = (int)(p >> 57);
    float wv = __uint_as_float((unsigned int)p);
    atomicAdd(&cnt[d7], 1u);
    atomicAdd(&wsum[d7], (unsigned int)__float2uint_rn(wv * WQ_SCALE));
  }
  __syncthreads();
  if (t < 128) sc[t] = (int)cnt[t];
  __syncthreads();
#pragma unroll
  for (int off = 1; off < 128; off <<= 1) {
    int y = 0;
    if (t < 128 && t >= off) y = sc[t - off];
    __syncthreads();
    if (t < 128 && t >= off) sc[t] += y;
    __syncthreads();
  }
  if (t < 128) {
    int node = (b << 7) + t;
    if (node < N) {
      rowstart[node] = r0 + sc[t] - (int)cnt[t];   // exclusive
      float deg = 1.0f + (float)wsum[t] * WQ_INV;  // self-loop + edge weights
      dinv[node] = rsqrtf(deg);
    }
  }
  if (b == 0 && t == 0) rowstart[N] = E;
}

// ============ Phase C2: per-bucket CSR fill ============
__launch_bounds__(256)
__global__ void c2_fill(const unsigned long long* __restrict__ bucketed,
                        const int* __restrict__ histS,
                        const int* __restrict__ rowstart, const float* __restrict__ dinv,
                        unsigned long long* __restrict__ colval,
                        int N, int E, int nbuck) {
  __shared__ unsigned int cursor[128];
  const int t = threadIdx.x;
  const int b = blockIdx.x;
  if (t < 128) {
    int node = (b << 7) + t;
    cursor[t] = (node < N) ? (unsigned int)rowstart[node] : 0u;
  }
  __syncthreads();
  const int r0 = histS[(size_t)b * 256];
  const int r1 = (b + 1 < nbuck) ? histS[(size_t)(b + 1) * 256] : E;
  for (int r = r0 + t; r < r1; r += 256) {
    unsigned long long p = bucketed[r];
    int d7 = (int)(p >> 57);
    int s = (int)((p >> 32) & 0x1FFFFFF);
    float wv = __uint_as_float((unsigned int)p);
    unsigned int pos = atomicAdd(&cursor[d7], 1u);
    float v = wv * dinv[s];
    colval[pos] = ((unsigned long long)(unsigned int)s << 32) |
                  (unsigned long long)__float_as_uint(v);
  }
}

// ---------------- GEMM: H16[N,64] = bf16(X[N,K] @ W[K,64])  (fp32 acc, VALU) -------
// Output H16 is consumed ONLY by k_agg (neighbor gathers + self term): bf16 store
// halves the gather payload to 1 cache line per edge (r9: k_agg is L2-miss-BW bound).
template <int K>
__launch_bounds__(256, 4)
__global__ void k_gemm(const float* __restrict__ X, const float* __restrict__ W,
                       unsigned short* __restrict__ H16, int N) {
  __shared__ float Xl[64 * 68];
  __shared__ float Wl[64 * 64];
  const int t = threadIdx.x;
  const int tx = t & 15;
  const int ty = t >> 4;
  const int n0 = blockIdx.x * 64;

  float4 acc[4];
#pragma unroll
  for (int r = 0; r < 4; ++r) acc[r] = make_float4(0.f, 0.f, 0.f, 0.f);

  for (int kt = 0; kt < K; kt += 64) {
    __syncthreads();
#pragma unroll
    for (int l = 0; l < 4; ++l) {
      int idx = t + l * 256;
      int node = idx >> 4;
      int kq = idx & 15;
      int gn = n0 + node;
      float4 v = make_float4(0.f, 0.f, 0.f, 0.f);
      if (gn < N) v = *(const float4*)(X + (size_t)gn * K + kt + 4 * kq);
      int kb = 4 * kq;
      Xl[(kb + 0) * 68 + node] = v.x;
      Xl[(kb + 1) * 68 + node] = v.y;
      Xl[(kb + 2) * 68 + node] = v.z;
      Xl[(kb + 3) * 68 + node] = v.w;
    }
#pragma unroll
    for (int l = 0; l < 4; ++l) {
      int idx = t + l * 256;
      ((float4*)Wl)[idx] = *(const float4*)(W + (size_t)(kt + (idx >> 4)) * 64 + 4 * (idx & 15));
    }
    __syncthreads();
#pragma unroll 8
    for (int k = 0; k < 64; ++k) {
      float4 xv = *(const float4*)(Xl + k * 68 + 4 * ty);
      float4 wv = *(const float4*)(Wl + k * 64 + 4 * tx);
      acc[0].x += xv.x * wv.x; acc[0].y += xv.x * wv.y; acc[0].z += xv.x * wv.z; acc[0].w += xv.x * wv.w;
      acc[1].x += xv.y * wv.x; acc[1].y += xv.y * wv.y; acc[1].z += xv.y * wv.z; acc[1].w += xv.y * wv.w;
      acc[2].x += xv.z * wv.x; acc[2].y += xv.z * wv.y; acc[2].z += xv.z * wv.z; acc[2].w += xv.z * wv.w;
      acc[3].x += xv.w * wv.x; acc[3].y += xv.w * wv.y; acc[3].z += xv.w * wv.z; acc[3].w += xv.w * wv.w;
    }
  }
#pragma unroll
  for (int r = 0; r < 4; ++r) {
    int gn = n0 + 4 * ty + r;
    if (gn < N) {
      ushort4 o;
      o.x = f2bf(acc[r].x); o.y = f2bf(acc[r].y);
      o.z = f2bf(acc[r].z); o.w = f2bf(acc[r].w);
      *(ushort4*)(H16 + (size_t)gn * 64 + 4 * tx) = o;
    }
  }
}

// ---------------- CSR aggregation, bf16 gather + 8-way MLP ----------------
// out[d] = dinv[d]*sum(val*h[src]) + dinv[d]^2*h[d] + b  (fp32 accumulate)
__launch_bounds__(256)
__global__ void k_agg(const unsigned short* __restrict__ h16, float* __restrict__ hout,
                      const float* __restrict__ bias, const float* __restrict__ dinv,
                      const int* __restrict__ rowstart,
                      const unsigned long long* __restrict__ colval,
                      int N, int apply_lrelu) {
  const int t = threadIdx.x;
  const int grp = t >> 4;
  const int lane = t & 15;
  const int d = blockIdx.x * 16 + grp;
  if (d >= N) return;
  const int r0 = rowstart[d];
  const int r1 = rowstart[d + 1];
  float4 a0 = make_float4(0.f, 0.f, 0.f, 0.f);
  float4 a1 = make_float4(0.f, 0.f, 0.f, 0.f);
  float4 a2 = make_float4(0.f, 0.f, 0.f, 0.f);
  float4 a3 = make_float4(0.f, 0.f, 0.f, 0.f);
  int r = r0;
  for (; r + 8 <= r1; r += 8) {
    unsigned long long cv0 = colval[r + 0];
    unsigned long long cv1 = colval[r + 1];
    unsigned long long cv2 = colval[r + 2];
    unsigned long long cv3 = colval[r + 3];
    unsigned long long cv4 = colval[r + 4];
    unsigned long long cv5 = colval[r + 5];
    unsigned long long cv6 = colval[r + 6];
    unsigned long long cv7 = colval[r + 7];
    ushort4 h0 = *(const ushort4*)(h16 + ((size_t)(cv0 >> 32)) * 64 + lane * 4);
    ushort4 h1 = *(const ushort4*)(h16 + ((size_t)(cv1 >> 32)) * 64 + lane * 4);
    ushort4 h2 = *(const ushort4*)(h16 + ((size_t)(cv2 >> 32)) * 64 + lane * 4);
    ushort4 h3 = *(const ushort4*)(h16 + ((size_t)(cv3 >> 32)) * 64 + lane * 4);
    ushort4 h4 = *(const ushort4*)(h16 + ((size_t)(cv4 >> 32)) * 64 + lane * 4);
    ushort4 h5 = *(const ushort4*)(h16 + ((size_t)(cv5 >> 32)) * 64 + lane * 4);
    ushort4 h6 = *(const ushort4*)(h16 + ((size_t)(cv6 >> 32)) * 64 + lane * 4);
    ushort4 h7 = *(const ushort4*)(h16 + ((size_t)(cv7 >> 32)) * 64 + lane * 4);
    float v0 = __uint_as_float((unsigned int)cv0);
    float v1 = __uint_as_float((unsigned int)cv1);
    float v2 = __uint_as_float((unsigned int)cv2);
    float v3 = __uint_as_float((unsigned int)cv3);
    float v4 = __uint_as_float((unsigned int)cv4);
    float v5 = __uint_as_float((unsigned int)cv5);
    float v6 = __uint_as_float((unsigned int)cv6);
    float v7 = __uint_as_float((unsigned int)cv7);
    a0.x += v0 * BF2F(h0.x); a0.y += v0 * BF2F(h0.y); a0.z += v0 * BF2F(h0.z); a0.w += v0 * BF2F(h0.w);
    a1.x += v1 * BF2F(h1.x); a1.y += v1 * BF2F(h1.y); a1.z += v1 * BF2F(h1.z); a1.w += v1 * BF2F(h1.w);
    a2.x += v2 * BF2F(h2.x); a2.y += v2 * BF2F(h2.y); a2.z += v2 * BF2F(h2.z); a2.w += v2 * BF2F(h2.w);
    a3.x += v3 * BF2F(h3.x); a3.y += v3 * BF2F(h3.y); a3.z += v3 * BF2F(h3.z); a3.w += v3 * BF2F(h3.w);
    a0.x += v4 * BF2F(h4.x); a0.y += v4 * BF2F(h4.y); a0.z += v4 * BF2F(h4.z); a0.w += v4 * BF2F(h4.w);
    a1.x += v5 * BF2F(h5.x); a1.y += v5 * BF2F(h5.y); a1.z += v5 * BF2F(h5.z); a1.w += v5 * BF2F(h5.w);
    a2.x += v6 * BF2F(h6.x); a2.y += v6 * BF2F(h6.y); a2.z += v6 * BF2F(h6.z); a2.w += v6 * BF2F(h6.w);
    a3.x += v7 * BF2F(h7.x); a3.y += v7 * BF2F(h7.y); a3.z += v7 * BF2F(h7.z); a3.w += v7 * BF2F(h7.w);
  }
  for (; r + 4 <= r1; r += 4) {
    unsigned long long cv0 = colval[r + 0];
    unsigned long long cv1 = colval[r + 1];
    unsigned long long cv2 = colval[r + 2];
    unsigned long long cv3 = colval[r + 3];
    ushort4 h0 = *(const ushort4*)(h16 + ((size_t)(cv0 >> 32)) * 64 + lane * 4);
    ushort4 h1 = *(const ushort4*)(h16 + ((size_t)(cv1 >> 32)) * 64 + lane * 4);
    ushort4 h2 = *(const ushort4*)(h16 + ((size_t)(cv2 >> 32)) * 64 + lane * 4);
    ushort4 h3 = *(const ushort4*)(h16 + ((size_t)(cv3 >> 32)) * 64 + lane * 4);
    float v0 = __uint_as_float((unsigned int)cv0);
    float v1 = __uint_as_float((unsigned int)cv1);
    float v2 = __uint_as_float((unsigned int)cv2);
    float v3 = __uint_as_float((unsigned int)cv3);
    a0.x += v0 * BF2F(h0.x); a0.y += v0 * BF2F(h0.y); a0.z += v0 * BF2F(h0.z); a0.w += v0 * BF2F(h0.w);
    a1.x += v1 * BF2F(h1.x); a1.y += v1 * BF2F(h1.y); a1.z += v1 * BF2F(h1.z); a1.w += v1 * BF2F(h1.w);
    a2.x += v2 * BF2F(h2.x); a2.y += v2 * BF2F(h2.y); a2.z += v2 * BF2F(h2.z); a2.w += v2 * BF2F(h2.w);
    a3.x += v3 * BF2F(h3.x); a3.y += v3 * BF2F(h3.y); a3.z += v3 * BF2F(h3.z); a3.w += v3 * BF2F(h3.w);
  }
  for (; r < r1; ++r) {
    unsigned long long cv = colval[r];
    float v = __uint_as_float((unsigned int)cv);
    ushort4 hv = *(const ushort4*)(h16 + ((size_t)(cv >> 32)) * 64 + lane * 4);
    a0.x += v * BF2F(hv.x); a0.y += v * BF2F(hv.y); a0.z += v * BF2F(hv.z); a0.w += v * BF2F(hv.w);
  }
  float4 acc;
  acc.x = (a0.x + a1.x) + (a2.x + a3.x);
  acc.y = (a0.y + a1.y) + (a2.y + a3.y);
  acc.z = (a0.z + a1.z) + (a2.z + a3.z);
  acc.w = (a0.w + a1.w) + (a2.w + a3.w);
  float di = dinv[d];
  float di2 = di * di;
  ushort4 hd4 = *(const ushort4*)(h16 + (size_t)d * 64 + lane * 4);
  float4 b4 = *(const float4*)(bias + lane * 4);
  float4 o;
  o.x = di * acc.x + di2 * BF2F(hd4.x) + b4.x;
  o.y = di * acc.y + di2 * BF2F(hd4.y) + b4.y;
  o.z = di * acc.z + di2 * BF2F(hd4.z) + b4.z;
  o.w = di * acc.w + di2 * BF2F(hd4.w) + b4.w;
  if (apply_lrelu) {
    o.x = (o.x > 0.f) ? o.x : LRELU_SLOPE * o.x;
    o.y = (o.y > 0.f) ? o.y : LRELU_SLOPE * o.y;
    o.z = (o.z > 0.f) ? o.z : LRELU_SLOPE * o.z;
    o.w = (o.w > 0.f) ? o.w : LRELU_SLOPE * o.w;
  }
  *(float4*)(hout + (size_t)d * 64 + lane * 4) = o;
}

// ---------------- BN column stats: per-block partials (atomic-free) ----------------
__launch_bounds__(256)
__global__ void k_stats(const float* __restrict__ h, float* __restrict__ partial, int N) {
  __shared__ float ls[256], lss[256];
  const int t = threadIdx.x;
  const int c = t & 63;
  float a = 0.f, a2 = 0.f;
  for (int n = blockIdx.x * 4 + (t >> 6); n < N; n += gridDim.x * 4) {
    float v = h[(size_t)n * 64 + c];
    a += v;
    a2 += v * v;
  }
  ls[t] = a;
  lss[t] = a2;
  __syncthreads();
  if (t < 64) {
    a = ls[t] + ls[t + 64] + ls[t + 128] + ls[t + 192];
    a2 = lss[t] + lss[t + 64] + lss[t + 128] + lss[t + 192];
    partial[blockIdx.x * 128 + t] = a;
    partial[blockIdx.x * 128 + 64 + t] = a2;
  }
}

// Parallel reduce: 128 blocks (one per output column), 256 threads each.
__global__ void k_stats_reduce(const float* __restrict__ partial, float* __restrict__ s,
                               float* __restrict__ ss, int nb) {
  __shared__ float red[256];
  const int c = blockIdx.x;   // 0..127
  const int t = threadIdx.x;  // 0..255
  float a = 0.f;
  for (int b = t; b < nb; b += 256) a += partial[(size_t)b * 128 + c];
  red[t] = a;
  __syncthreads();
  for (int st = 128; st >= 1; st >>= 1) {
    if (t < st) red[t] += red[t + st];
    __syncthreads();
  }
  if (t == 0) {
    if (c < 64) s[c] = red[0];
    else ss[c - 64] = red[0];
  }
}

// ---------------- BN apply + LeakyReLU ----------------
__launch_bounds__(256)
__global__ void k_bnapply(const float* __restrict__ hin, float* __restrict__ hout,
                          const float* __restrict__ s, const float* __restrict__ ss,
                          const float* __restrict__ g, const float* __restrict__ be,
                          int N) {
  int i = blockIdx.x * blockDim.x + threadIdx.x;  // index over N*16 float4s
  if (i >= N * 16) return;
  int c0 = (i & 15) * 4;
  float invN = 1.0f / (float)N;
  float4 v = ((const float4*)hin)[i];
  float o[4] = {v.x, v.y, v.z, v.w};
#pragma unroll
  for (int k = 0; k < 4; ++k) {
    int c = c0 + k;
    float mean = s[c] * invN;
    float var = ss[c] * invN - mean * mean;
    float scale = g[c] * rsqrtf(var + BN_EPS);
    float r = (o[k] - mean) * scale + be[c];
    o[k] = (r > 0.f) ? r : LRELU_SLOPE * r;
  }
  ((float4*)hout)[i] = make_float4(o[0], o[1], o[2], o[3]);
}

// ---------------- graph boundaries from sorted batch (atomic-free) ----------------
__global__ void k_gbounds(const int* __restrict__ batch, int* __restrict__ gstart,
                          int N, int G) {
  int i = blockIdx.x * blockDim.x + threadIdx.x;
  if (i >= N) return;
  int b = batch[i];
  int prev = (i == 0) ? -1 : batch[i - 1];
  for (int g = prev + 1; g <= b; ++g) gstart[g] = i;   // batch sorted => prev <= b
  if (i == N - 1) {
    for (int g = b + 1; g <= G; ++g) gstart[g] = N;
  }
}

// ---------------- pooling (max & mean per graph) + FC, fused ----------------
__launch_bounds__(256)
__global__ void k_pool(const float* __restrict__ h, const int* __restrict__ gstart,
                       const float* __restrict__ Wfc, const float* __restrict__ bfc,
                       float* __restrict__ out, int G) {
  __shared__ float lmx[256], lsm[256], red[128];
  const int g = blockIdx.x;
  const int t = threadIdx.x;
  const int c = t & 63;
  const int sub = t >> 6;
  const int n0 = gstart[g];
  const int n1 = gstart[g + 1];
  float mx = -INFINITY, sm = 0.f;
  for (int n = n0 + sub; n < n1; n += 4) {
    float v = h[(size_t)n * 64 + c];
    mx = fmaxf(mx, v);
    sm += v;
  }
  lmx[t] = mx;
  lsm[t] = sm;
  __syncthreads();
  if (t < 64) {
    mx = fmaxf(fmaxf(lmx[t], lmx[t + 64]), fmaxf(lmx[t + 128], lmx[t + 192]));
    sm = lsm[t] + lsm[t + 64] + lsm[t + 128] + lsm[t + 192];
    float cntf = (float)(n1 - n0);
    float mean = sm / fmaxf(cntf, 1.0f);
    red[t] = mx * Wfc[t];
    red[t + 64] = mean * Wfc[64 + t];
  }
  __syncthreads();
  for (int st = 64; st >= 1; st >>= 1) {
    if (t < st) red[t] += red[t + st];
    __syncthreads();
  }
  if (t == 0) out[g] = red[0] + bfc[0];
}

// ---------------- host launch ----------------
extern "C" void kernel_launch(void* const* d_in, const int* in_sizes, int n_in,
                              void* d_out, int out_size, void* d_ws, size_t ws_size,
                              hipStream_t stream) {
  const float* x = (const float*)d_in[0];
  const int* ei = (const int*)d_in[1];
  const int* batch = (const int*)d_in[2];
  const float* eattr = (const float*)d_in[3];
  const float* W0 = (const float*)d_in[4];
  const float* b0 = (const float*)d_in[5];
  const float* g0 = (const float*)d_in[6];
  const float* be0 = (const float*)d_in[7];
  const float* W1 = (const float*)d_in[8];
  const float* b1 = (const float*)d_in[9];
  const float* g1 = (const float*)d_in[10];
  const float* be1 = (const float*)d_in[11];
  const float* W2 = (const float*)d_in[12];
  const float* b2 = (const float*)d_in[13];
  const float* W3 = (const float*)d_in[14];
  const float* b3 = (const float*)d_in[15];
  const float* Wfc = (const float*)d_in[16];
  const float* bfc = (const float*)d_in[17];
  float* out = (float*)d_out;

  const int N = in_sizes[2];       // batch is [N]
  const int E = in_sizes[3];       // edge_attr is [E]
  const int CIN = in_sizes[0] / N; // 128
  const int G = out_size;          // [G,1]
  const int nbuck = ceil_div(N, 128);
  const int chunk = ceil_div(E, 256);
  const int M = nbuck * 256;       // hist matrix elements

  // workspace carve-up (256B-aligned slices)
  size_t off = 0;
  auto alloc = [&](size_t bytes) -> void* {
    void* p = (char*)d_ws + off;
    off += (bytes + 255) & ~(size_t)255;
    return p;
  };
  int* histT = (int*)alloc((size_t)1024 * 256 * 4);   // raw counts [bucket][block]
  int* histS = (int*)alloc((size_t)1024 * 256 * 4);   // scanned
  int* bsum = (int*)alloc(1024 * 4);
  unsigned long long* bucketed = (unsigned long long*)alloc((size_t)E * 8);
  float* dinv = (float*)alloc((size_t)N * 4);
  int* rowstart = (int*)alloc((size_t)(N + 1) * 4);
  unsigned long long* colval = (unsigned long long*)alloc((size_t)E * 8);
  float* A = (float*)alloc((size_t)N * 64 * 4);
  float* B = (float*)alloc((size_t)N * 64 * 4);
  unsigned short* H16 = (unsigned short*)alloc((size_t)N * 64 * 2);
  float* sums = (float*)alloc(256 * 4);   // s0|ss0|s1|ss1
  float* partial = (float*)alloc(256 * 128 * 4);
  int* gstart = (int*)alloc((size_t)(G + 1) * 4);
  (void)ws_size; (void)n_in; (void)CIN;

  // ---- graph structure (layer-invariant, zero device-scope atomics) ----
  b1_hist<<<256, 256, 0, stream>>>(ei, histT, E, chunk, nbuck);
  const int nbs = ceil_div(M, 1024);
  scan1i<<<nbs, 256, 0, stream>>>(histT, histS, bsum, M);
  scan2i<<<1, 256, 0, stream>>>(bsum, nbs);
  scan3i<<<ceil_div(M, 256), 256, 0, stream>>>(histS, bsum, M);
  b3_scatter<<<256, 256, 0, stream>>>(ei, eattr, histS, bucketed, E, chunk, nbuck);
  c1_degree<<<nbuck, 256, 0, stream>>>(bucketed, histS, rowstart, dinv, N, E, nbuck);
  c2_fill<<<nbuck, 256, 0, stream>>>(bucketed, histS, rowstart, dinv, colval, N, E, nbuck);
  k_gbounds<<<ceil_div(N, 256), 256, 0, stream>>>(batch, gstart, N, G);

  // layer 0: gemm(x,W0)->H16; agg H16->B; stats(B); bn+lrelu B->A
  k_gemm<128><<<ceil_div(N, 64), 256, 0, stream>>>(x, W0, H16, N);
  k_agg<<<ceil_div(N, 16), 256, 0, stream>>>(H16, B, b0, dinv, rowstart, colval, N, 0);
  k_stats<<<256, 256, 0, stream>>>(B, partial, N);
  k_stats_reduce<<<128, 256, 0, stream>>>(partial, sums + 0, sums + 64, 256);
  k_bnapply<<<ceil_div(N * 16, 256), 256, 0, stream>>>(B, A, sums + 0, sums + 64, g0, be0, N);

  // layer 1: gemm(A,W1)->H16; agg H16->B; stats(B); bn+lrelu B->A
  k_gemm<64><<<ceil_div(N, 64), 256, 0, stream>>>(A, W1, H16, N);
  k_agg<<<ceil_div(N, 16), 256, 0, stream>>>(H16, B, b1, dinv, rowstart, colval, N, 0);
  k_stats<<<256, 256, 0, stream>>>(B, partial, N);
  k_stats_reduce<<<128, 256, 0, stream>>>(partial, sums + 128, sums + 192, 256);
  k_bnapply<<<ceil_div(N * 16, 256), 256, 0, stream>>>(B, A, sums + 128, sums + 192, g1, be1, N);

  // layer 2: gemm(A,W2)->H16; agg(+lrelu) H16->B
  k_gemm<64><<<ceil_div(N, 64), 256, 0, stream>>>(A, W2, H16, N);
  k_agg<<<ceil_div(N, 16), 256, 0, stream>>>(H16, B, b2, dinv, rowstart, colval, N, 1);

  // layer 3: gemm(B,W3)->H16; agg(+lrelu) H16->A
  k_gemm<64><<<ceil_div(N, 64), 256, 0, stream>>>(B, W3, H16, N);
  k_agg<<<ceil_div(N, 16), 256, 0, stream>>>(H16, A, b3, dinv, rowstart, colval, N, 1);

  // pooling + FC
  k_pool<<<G, 256, 0, stream>>>(A, gstart, Wfc, bfc, out, G);
}